// Round 1
// baseline (1302.496 us; speedup 1.0000x reference)
//
#include <hip/hip_runtime.h>

#define T_    16
#define M_    256
#define HW_   1024
#define DM    512
#define H_    8
#define HEAD_ 64

// ---------------------------------------------------------------------------
// C[R x 512] = X[R x 512] @ W[512 x 512]^T   (torch Linear)
// Both X and W are k-contiguous (row-major), tile 64x64, BK=32, 256 threads.
// ---------------------------------------------------------------------------
__global__ __launch_bounds__(256) void gemm_xwt(const float* __restrict__ X,
                                                const float* __restrict__ W,
                                                float* __restrict__ C) {
    __shared__ float As[32][65];  // [k][row] transposed stage, +1 pad
    __shared__ float Bs[32][65];  // [k][col]
    const int tid  = threadIdx.x;
    const int row0 = blockIdx.y * 64;
    const int col0 = blockIdx.x * 64;
    const int ty = tid / 16, tx = tid % 16;

    float acc[4][4] = {};

    for (int k0 = 0; k0 < DM; k0 += 32) {
        const int d = tid % 32;
        const int r = tid / 32;  // 0..7
        #pragma unroll
        for (int i = 0; i < 8; ++i) {
            As[d][r + i * 8] = X[(size_t)(row0 + r + i * 8) * DM + k0 + d];
            Bs[d][r + i * 8] = W[(size_t)(col0 + r + i * 8) * DM + k0 + d];
        }
        __syncthreads();
        #pragma unroll
        for (int d2 = 0; d2 < 32; ++d2) {
            float a[4], b[4];
            #pragma unroll
            for (int i = 0; i < 4; ++i) a[i] = As[d2][ty * 4 + i];
            #pragma unroll
            for (int j = 0; j < 4; ++j) b[j] = Bs[d2][tx * 4 + j];
            #pragma unroll
            for (int i = 0; i < 4; ++i)
                #pragma unroll
                for (int j = 0; j < 4; ++j) acc[i][j] += a[i] * b[j];
        }
        __syncthreads();
    }

    #pragma unroll
    for (int i = 0; i < 4; ++i) {
        float4 v = make_float4(acc[i][0], acc[i][1], acc[i][2], acc[i][3]);
        *reinterpret_cast<float4*>(
            &C[(size_t)(row0 + ty * 4 + i) * DM + col0 + tx * 4]) = v;
    }
}

// ---------------------------------------------------------------------------
// In-place LayerNorm (no bias) over rows of 512, one wave (64 lanes) per row.
// ---------------------------------------------------------------------------
__global__ __launch_bounds__(256) void ln_rows(float* __restrict__ X,
                                               const float* __restrict__ gamma,
                                               int nrows) {
    const int wave = threadIdx.x / 64;
    const int lane = threadIdx.x % 64;
    const int row  = blockIdx.x * 4 + wave;
    if (row >= nrows) return;

    float4 v0 = *reinterpret_cast<const float4*>(&X[(size_t)row * DM + lane * 8]);
    float4 v1 = *reinterpret_cast<const float4*>(&X[(size_t)row * DM + lane * 8 + 4]);
    float x[8] = {v0.x, v0.y, v0.z, v0.w, v1.x, v1.y, v1.z, v1.w};

    float s = 0.f;
    #pragma unroll
    for (int i = 0; i < 8; ++i) s += x[i];
    #pragma unroll
    for (int m = 1; m < 64; m <<= 1) s += __shfl_xor(s, m, 64);
    const float mu = s * (1.0f / 512.0f);

    float vs = 0.f;
    #pragma unroll
    for (int i = 0; i < 8; ++i) { float d = x[i] - mu; vs += d * d; }
    #pragma unroll
    for (int m = 1; m < 64; m <<= 1) vs += __shfl_xor(vs, m, 64);
    const float rs = rsqrtf(vs * (1.0f / 512.0f) + 1e-6f);

    float4 g0 = *reinterpret_cast<const float4*>(&gamma[lane * 8]);
    float4 g1 = *reinterpret_cast<const float4*>(&gamma[lane * 8 + 4]);
    float g[8] = {g0.x, g0.y, g0.z, g0.w, g1.x, g1.y, g1.z, g1.w};

    float y[8];
    #pragma unroll
    for (int i = 0; i < 8; ++i) y[i] = (x[i] - mu) * rs * g[i];
    *reinterpret_cast<float4*>(&X[(size_t)row * DM + lane * 8]) =
        make_float4(y[0], y[1], y[2], y[3]);
    *reinterpret_cast<float4*>(&X[(size_t)row * DM + lane * 8 + 4]) =
        make_float4(y[4], y[5], y[6], y[7]);
}

// ---------------------------------------------------------------------------
// Fused attention: per block = (t, h, 32-query tile).
// scores = Qh Kh^T / 8  - 2*d2 ; softmax over 256 keys ; upd = attn @ Vh
// ---------------------------------------------------------------------------
__global__ __launch_bounds__(256) void attn_fused(const float* __restrict__ Q,
                                                  const float* __restrict__ K,
                                                  const float* __restrict__ V,
                                                  const float* __restrict__ tracks,
                                                  const float* __restrict__ fpos,
                                                  float* __restrict__ U) {
    const int t  = blockIdx.z;
    const int h  = blockIdx.y;
    const int q0 = blockIdx.x * 32;
    const int tid = threadIdx.x;

    __shared__ float Qs[32][65];
    __shared__ float KVs[64][65];
    __shared__ float Ss[32][257];
    __shared__ float trk[256][2];
    __shared__ float fps[32][2];

    // stage Q tile (32 x 64)
    {
        const int d = tid % 64, q = tid / 64;  // q in 0..3
        #pragma unroll
        for (int i = 0; i < 8; ++i)
            Qs[q + i * 4][d] =
                Q[(size_t)(t * HW_ + q0 + q + i * 4) * DM + h * HEAD_ + d];
    }
    // stage tracks[t] (256 x 2) and fpos tile (32 x 2)
    #pragma unroll
    for (int i = 0; i < 2; ++i) {
        int e = tid + i * 256;  // 0..511
        trk[e >> 1][e & 1] = tracks[(size_t)(t * M_) * 2 + e];
    }
    if (tid < 64) fps[tid >> 1][tid & 1] = fpos[(size_t)q0 * 2 + tid];

    const int qg = tid / 32;  // 0..7  -> q rows qg*4 + i
    const int kg = tid % 32;  // 0..31 -> keys  c*64 + kg*2 + j

    float s[32];  // [c][i][j] -> c*8 + i*2 + j  (all static indexing)

    // ---- scores: 4 chunks of 64 keys ----
    #pragma unroll
    for (int c = 0; c < 4; ++c) {
        __syncthreads();
        {
            const int d = tid % 64, kk = tid / 64;
            #pragma unroll
            for (int i = 0; i < 16; ++i)
                KVs[kk + i * 4][d] =
                    K[(size_t)(t * M_ + c * 64 + kk + i * 4) * DM + h * HEAD_ + d];
        }
        __syncthreads();
        float acc[4][2] = {};
        #pragma unroll
        for (int d = 0; d < 64; ++d) {
            float a[4], b[2];
            #pragma unroll
            for (int i = 0; i < 4; ++i) a[i] = Qs[qg * 4 + i][d];
            #pragma unroll
            for (int j = 0; j < 2; ++j) b[j] = KVs[kg * 2 + j][d];
            #pragma unroll
            for (int i = 0; i < 4; ++i)
                #pragma unroll
                for (int j = 0; j < 2; ++j) acc[i][j] += a[i] * b[j];
        }
        #pragma unroll
        for (int i = 0; i < 4; ++i)
            #pragma unroll
            for (int j = 0; j < 2; ++j) s[c * 8 + i * 2 + j] = acc[i][j];
    }

    // ---- scale + spatial bias ----
    #pragma unroll
    for (int i = 0; i < 4; ++i) {
        const float fx = fps[qg * 4 + i][0], fy = fps[qg * 4 + i][1];
        #pragma unroll
        for (int c = 0; c < 4; ++c)
            #pragma unroll
            for (int j = 0; j < 2; ++j) {
                const int k = c * 64 + kg * 2 + j;
                const float dx = fx - trk[k][0];
                const float dy = fy - trk[k][1];
                s[c * 8 + i * 2 + j] =
                    s[c * 8 + i * 2 + j] * 0.125f - 2.0f * (dx * dx + dy * dy);
            }
    }

    // ---- softmax over 256 keys per row (32 lanes hold a row) ----
    #pragma unroll
    for (int i = 0; i < 4; ++i) {
        float m = -1e30f;
        #pragma unroll
        for (int c = 0; c < 4; ++c)
            #pragma unroll
            for (int j = 0; j < 2; ++j) m = fmaxf(m, s[c * 8 + i * 2 + j]);
        #pragma unroll
        for (int b = 1; b < 32; b <<= 1) m = fmaxf(m, __shfl_xor(m, b, 64));
        float sum = 0.f;
        #pragma unroll
        for (int c = 0; c < 4; ++c)
            #pragma unroll
            for (int j = 0; j < 2; ++j) {
                float e = __expf(s[c * 8 + i * 2 + j] - m);
                s[c * 8 + i * 2 + j] = e;
                sum += e;
            }
        #pragma unroll
        for (int b = 1; b < 32; b <<= 1) sum += __shfl_xor(sum, b, 64);
        const float inv = 1.0f / sum;
        #pragma unroll
        for (int c = 0; c < 4; ++c)
            #pragma unroll
            for (int j = 0; j < 2; ++j)
                Ss[qg * 4 + i][c * 64 + kg * 2 + j] = s[c * 8 + i * 2 + j] * inv;
    }

    // ---- PV: upd[32 x 64] ----
    const int qq = tid / 16;  // 0..15 -> q rows qq*2 + i
    const int dq = tid % 16;  // dv = dq*4 + j
    float acc2[2][4] = {};
    #pragma unroll
    for (int c = 0; c < 4; ++c) {
        __syncthreads();
        {
            const int d = tid % 64, kk = tid / 64;
            #pragma unroll
            for (int i = 0; i < 16; ++i)
                KVs[kk + i * 4][d] =
                    V[(size_t)(t * M_ + c * 64 + kk + i * 4) * DM + h * HEAD_ + d];
        }
        __syncthreads();
        #pragma unroll
        for (int k = 0; k < 64; ++k) {
            const float a0 = Ss[qq * 2 + 0][c * 64 + k];
            const float a1 = Ss[qq * 2 + 1][c * 64 + k];
            float b[4];
            #pragma unroll
            for (int j = 0; j < 4; ++j) b[j] = KVs[k][dq * 4 + j];
            #pragma unroll
            for (int j = 0; j < 4; ++j) {
                acc2[0][j] += a0 * b[j];
                acc2[1][j] += a1 * b[j];
            }
        }
    }
    #pragma unroll
    for (int i = 0; i < 2; ++i) {
        float4 v = make_float4(acc2[i][0], acc2[i][1], acc2[i][2], acc2[i][3]);
        *reinterpret_cast<float4*>(
            &U[(size_t)(t * HW_ + q0 + qq * 2 + i) * DM + h * HEAD_ + dq * 4]) = v;
    }
}

// ---------------------------------------------------------------------------
extern "C" void kernel_launch(void* const* d_in, const int* in_sizes, int n_in,
                              void* d_out, int out_size, void* d_ws, size_t ws_size,
                              hipStream_t stream) {
    const float* utt    = (const float*)d_in[0];   // updated_track_tokens [T,M,512]
    const float* tracks = (const float*)d_in[1];   // [T,M,2]
    const float* fpos   = (const float*)d_in[2];   // [HW,2]
    const float* fpe    = (const float*)d_in[3];   // [T,HW,512]
    const float* tpe    = (const float*)d_in[4];   // [T,M,512]
    const float* Wq     = (const float*)d_in[5];
    const float* Wk     = (const float*)d_in[6];
    const float* Wv     = (const float*)d_in[7];
    const float* Wo     = (const float*)d_in[8];
    const float* qgamma = (const float*)d_in[9];
    const float* kgamma = (const float*)d_in[10];
    float* out = (float*)d_out;

    char* ws = (char*)d_ws;
    float* Q  = (float*)(ws);                      // 16384*512*4 = 33554432
    float* Kp = (float*)(ws + 33554432);           //  4096*512*4 =  8388608
    float* Vp = (float*)(ws + 41943040);           //  4096*512*4 =  8388608
    float* U  = (float*)(ws + 50331648);           // 16384*512*4 = 33554432

    // Projections
    gemm_xwt<<<dim3(8, 256), 256, 0, stream>>>(fpe, Wq, Q);    // Q = fpe @ Wq^T
    gemm_xwt<<<dim3(8, 64),  256, 0, stream>>>(tpe, Wk, Kp);   // K = tpe @ Wk^T
    gemm_xwt<<<dim3(8, 64),  256, 0, stream>>>(utt, Wv, Vp);   // V = utt @ Wv^T

    // QK LayerNorm (full d_k rows, before head split)
    ln_rows<<<4096, 256, 0, stream>>>(Q,  qgamma, 16384);
    ln_rows<<<1024, 256, 0, stream>>>(Kp, kgamma, 4096);

    // Fused attention with spatial bias
    attn_fused<<<dim3(32, 8, 16), 256, 0, stream>>>(Q, Kp, Vp, tracks, fpos, U);

    // Out projection
    gemm_xwt<<<dim3(8, 256), 256, 0, stream>>>(U, Wo, out);    // out = U @ Wo^T
}

// Round 3
// 492.764 us; speedup vs baseline: 2.6432x; 2.6432x over previous
//
#include <hip/hip_runtime.h>

#define T_    16
#define M_    256
#define HW_   1024
#define DM    512
#define H_    8
#define HEAD_ 64

typedef __attribute__((ext_vector_type(8))) short short8;
typedef __attribute__((ext_vector_type(4))) float f32x4;

__device__ __forceinline__ unsigned short bf16b(float x) {
    unsigned u = __float_as_uint(x);
    unsigned r = (u + 0x7FFFu + ((u >> 16) & 1u)) >> 16;
    return (unsigned short)r;
}

// ---------------------------------------------------------------------------
// C[R x 512] = X[R x 512] @ W[512 x 512]^T   (f32)
// ---------------------------------------------------------------------------
__global__ __launch_bounds__(256) void gemm_xwt(const float* __restrict__ X,
                                                const float* __restrict__ W,
                                                float* __restrict__ C) {
    __shared__ float As[32][65];
    __shared__ float Bs[32][65];
    const int tid  = threadIdx.x;
    const int row0 = blockIdx.y * 64;
    const int col0 = blockIdx.x * 64;
    const int ty = tid / 16, tx = tid % 16;

    float acc[4][4] = {};

    for (int k0 = 0; k0 < DM; k0 += 32) {
        const int d = tid % 32;
        const int r = tid / 32;
        #pragma unroll
        for (int i = 0; i < 8; ++i) {
            As[d][r + i * 8] = X[(size_t)(row0 + r + i * 8) * DM + k0 + d];
            Bs[d][r + i * 8] = W[(size_t)(col0 + r + i * 8) * DM + k0 + d];
        }
        __syncthreads();
        #pragma unroll
        for (int d2 = 0; d2 < 32; ++d2) {
            float a[4], b[4];
            #pragma unroll
            for (int i = 0; i < 4; ++i) a[i] = As[d2][ty * 4 + i];
            #pragma unroll
            for (int j = 0; j < 4; ++j) b[j] = Bs[d2][tx * 4 + j];
            #pragma unroll
            for (int i = 0; i < 4; ++i)
                #pragma unroll
                for (int j = 0; j < 4; ++j) acc[i][j] += a[i] * b[j];
        }
        __syncthreads();
    }

    #pragma unroll
    for (int i = 0; i < 4; ++i) {
        float4 v = make_float4(acc[i][0], acc[i][1], acc[i][2], acc[i][3]);
        *reinterpret_cast<float4*>(
            &C[(size_t)(row0 + ty * 4 + i) * DM + col0 + tx * 4]) = v;
    }
}

// ---------------------------------------------------------------------------
// In-place f32 LayerNorm (no bias), one wave per 512-row.
// ---------------------------------------------------------------------------
__global__ __launch_bounds__(256) void ln_rows(float* __restrict__ X,
                                               const float* __restrict__ gamma,
                                               int nrows) {
    const int wave = threadIdx.x / 64;
    const int lane = threadIdx.x % 64;
    const int row  = blockIdx.x * 4 + wave;
    if (row >= nrows) return;

    float4 v0 = *reinterpret_cast<const float4*>(&X[(size_t)row * DM + lane * 8]);
    float4 v1 = *reinterpret_cast<const float4*>(&X[(size_t)row * DM + lane * 8 + 4]);
    float x[8] = {v0.x, v0.y, v0.z, v0.w, v1.x, v1.y, v1.z, v1.w};

    float s = 0.f;
    #pragma unroll
    for (int i = 0; i < 8; ++i) s += x[i];
    #pragma unroll
    for (int m = 1; m < 64; m <<= 1) s += __shfl_xor(s, m, 64);
    const float mu = s * (1.0f / 512.0f);

    float vs = 0.f;
    #pragma unroll
    for (int i = 0; i < 8; ++i) { float d = x[i] - mu; vs += d * d; }
    #pragma unroll
    for (int m = 1; m < 64; m <<= 1) vs += __shfl_xor(vs, m, 64);
    const float rs = rsqrtf(vs * (1.0f / 512.0f) + 1e-6f);

    float4 g0 = *reinterpret_cast<const float4*>(&gamma[lane * 8]);
    float4 g1 = *reinterpret_cast<const float4*>(&gamma[lane * 8 + 4]);
    float g[8] = {g0.x, g0.y, g0.z, g0.w, g1.x, g1.y, g1.z, g1.w};

    float y[8];
    #pragma unroll
    for (int i = 0; i < 8; ++i) y[i] = (x[i] - mu) * rs * g[i];
    *reinterpret_cast<float4*>(&X[(size_t)row * DM + lane * 8]) =
        make_float4(y[0], y[1], y[2], y[3]);
    *reinterpret_cast<float4*>(&X[(size_t)row * DM + lane * 8 + 4]) =
        make_float4(y[4], y[5], y[6], y[7]);
}

// ---------------------------------------------------------------------------
// V [T*M][512] f32  ->  Vt [T][512 dv][256 key] bf16 (transpose + cast)
// 64x64 tile = 1024 float4 / ushort4 -> 4 iters of 256 threads.
// ---------------------------------------------------------------------------
__global__ __launch_bounds__(256) void vtrans(const float* __restrict__ V,
                                              unsigned short* __restrict__ Vt) {
    const int t = blockIdx.z, kt = blockIdx.y, dt = blockIdx.x;
    __shared__ float tile[64][65];
    const int tid = threadIdx.x;

    #pragma unroll
    for (int i = 0; i < 4; ++i) {
        int idx = tid + i * 256;           // 0..1023
        int r = idx >> 4, c4 = idx & 15;   // r = key-local 0..63, c4*4 = dv-local
        float4 v = *reinterpret_cast<const float4*>(
            &V[(size_t)(t * M_ + kt * 64 + r) * DM + dt * 64 + c4 * 4]);
        tile[r][c4 * 4 + 0] = v.x;
        tile[r][c4 * 4 + 1] = v.y;
        tile[r][c4 * 4 + 2] = v.z;
        tile[r][c4 * 4 + 3] = v.w;
    }
    __syncthreads();
    #pragma unroll
    for (int i = 0; i < 4; ++i) {
        int idx = tid + i * 256;           // 0..1023
        int r = idx >> 4, c4 = idx & 15;   // r = dv-local 0..63, c4*4 = key-local
        ushort4 o;
        o.x = bf16b(tile[c4 * 4 + 0][r]);
        o.y = bf16b(tile[c4 * 4 + 1][r]);
        o.z = bf16b(tile[c4 * 4 + 2][r]);
        o.w = bf16b(tile[c4 * 4 + 3][r]);
        *reinterpret_cast<ushort4*>(
            &Vt[((size_t)t * DM + dt * 64 + r) * M_ + kt * 64 + c4 * 4]) = o;
    }
}

// ---------------------------------------------------------------------------
// MFMA attention. Block = (qtile=64, h, t), 4 waves, wave owns 16 q-rows.
// scores = (Q K^T)/8 - 2*d2 ; softmax over 256 keys ; U = P V
// ---------------------------------------------------------------------------
__global__ __launch_bounds__(256) void attn_mfma(const float* __restrict__ Qf,
                                                 const float* __restrict__ Kf,
                                                 const unsigned short* __restrict__ VtG,
                                                 const float* __restrict__ tracks,
                                                 const float* __restrict__ fpos,
                                                 float* __restrict__ U) {
    const int t  = blockIdx.z;
    const int h  = blockIdx.y;
    const int q0 = blockIdx.x * 64;
    const int tid = threadIdx.x;

    __shared__ __align__(16) unsigned char smem[76288];
    unsigned char* Qs = smem;              // [64 q ][64 d ] bf16 swz, 8192 B
    unsigned char* KV = smem + 8192;       // K:[256 k][64 d] / V:[64 dv][256 k], 32768 B
    unsigned char* Ps = smem + 40960;      // [64 q ][256 k] bf16 swz, 32768 B
    float* trk = (float*)(smem + 73728);   // 512 f32
    float* fps = (float*)(smem + 75776);   // 128 f32

    // ---- stage Q (f32 -> bf16, swizzled) ----
    #pragma unroll
    for (int i = 0; i < 2; ++i) {
        int idx = tid + i * 256;           // 0..511
        int row = idx >> 3, dc = idx & 7;
        const float* src = Qf + (size_t)(t * HW_ + q0 + row) * DM + h * HEAD_ + dc * 8;
        float4 a = *reinterpret_cast<const float4*>(src);
        float4 b = *reinterpret_cast<const float4*>(src + 4);
        short8 v;
        v[0] = bf16b(a.x); v[1] = bf16b(a.y); v[2] = bf16b(a.z); v[3] = bf16b(a.w);
        v[4] = bf16b(b.x); v[5] = bf16b(b.y); v[6] = bf16b(b.z); v[7] = bf16b(b.w);
        *reinterpret_cast<short8*>(Qs + ((row * 128 + dc * 16) ^ ((row & 7) << 4))) = v;
    }
    // ---- stage K ----
    #pragma unroll
    for (int i = 0; i < 8; ++i) {
        int idx = tid + i * 256;           // 0..2047
        int row = idx >> 3, dc = idx & 7;
        const float* src = Kf + (size_t)(t * M_ + row) * DM + h * HEAD_ + dc * 8;
        float4 a = *reinterpret_cast<const float4*>(src);
        float4 b = *reinterpret_cast<const float4*>(src + 4);
        short8 v;
        v[0] = bf16b(a.x); v[1] = bf16b(a.y); v[2] = bf16b(a.z); v[3] = bf16b(a.w);
        v[4] = bf16b(b.x); v[5] = bf16b(b.y); v[6] = bf16b(b.z); v[7] = bf16b(b.w);
        *reinterpret_cast<short8*>(KV + ((row * 128 + dc * 16) ^ ((row & 7) << 4))) = v;
    }
    // ---- stage tracks + fpos ----
    trk[tid]       = tracks[(size_t)t * M_ * 2 + tid];
    trk[tid + 256] = tracks[(size_t)t * M_ * 2 + tid + 256];
    if (tid < 128) fps[tid] = fpos[(size_t)q0 * 2 + tid];
    __syncthreads();

    const int l = tid & 63;
    const int wq = tid >> 6;
    const int g = l >> 4;      // 0..3
    const int c = l & 15;      // 0..15

    // ---- scores: Q-rows wq*16..+15 x 256 keys ----
    const int rq = wq * 16 + c;
    short8 aQ0 = *reinterpret_cast<short8*>(Qs + ((rq * 128 +  0 + g * 16) ^ ((rq & 7) << 4)));
    short8 aQ1 = *reinterpret_cast<short8*>(Qs + ((rq * 128 + 64 + g * 16) ^ ((rq & 7) << 4)));

    f32x4 acc[16];
    #pragma unroll
    for (int n = 0; n < 16; ++n) {
        int rk = n * 16 + c;
        short8 b0 = *reinterpret_cast<short8*>(KV + ((rk * 128 +  0 + g * 16) ^ ((rk & 7) << 4)));
        short8 b1 = *reinterpret_cast<short8*>(KV + ((rk * 128 + 64 + g * 16) ^ ((rk & 7) << 4)));
        f32x4 z = {0.f, 0.f, 0.f, 0.f};
        z = __builtin_amdgcn_mfma_f32_16x16x32_bf16(aQ0, b0, z, 0, 0, 0);
        z = __builtin_amdgcn_mfma_f32_16x16x32_bf16(aQ1, b1, z, 0, 0, 0);
        acc[n] = z;   // acc[n][r]: score[q = wq*16+g*4+r][key = n*16+c]
    }

    // ---- bias ----
    float fx[4], fy[4];
    #pragma unroll
    for (int r = 0; r < 4; ++r) {
        int ql = wq * 16 + g * 4 + r;
        fx[r] = fps[ql * 2]; fy[r] = fps[ql * 2 + 1];
    }
    #pragma unroll
    for (int n = 0; n < 16; ++n) {
        float2 tk = *reinterpret_cast<float2*>(&trk[(n * 16 + c) * 2]);
        #pragma unroll
        for (int r = 0; r < 4; ++r) {
            float dx = fx[r] - tk.x, dy = fy[r] - tk.y;
            acc[n][r] = acc[n][r] * 0.125f - 2.0f * (dx * dx + dy * dy);
        }
    }

    // ---- softmax over keys (16 in-lane x 16 lanes) + P write (bf16, swz) ----
    #pragma unroll
    for (int r = 0; r < 4; ++r) {
        float m = acc[0][r];
        #pragma unroll
        for (int n = 1; n < 16; ++n) m = fmaxf(m, acc[n][r]);
        #pragma unroll
        for (int b = 1; b < 16; b <<= 1) m = fmaxf(m, __shfl_xor(m, b, 64));
        float s = 0.f;
        #pragma unroll
        for (int n = 0; n < 16; ++n) { float e = __expf(acc[n][r] - m); acc[n][r] = e; s += e; }
        #pragma unroll
        for (int b = 1; b < 16; b <<= 1) s += __shfl_xor(s, b, 64);
        const float inv = 1.0f / s;
        const int row = wq * 16 + g * 4 + r;
        #pragma unroll
        for (int n = 0; n < 16; ++n) {
            int key = n * 16 + c;
            *reinterpret_cast<unsigned short*>(
                Ps + ((row * 512 + key * 2) ^ ((row & 7) << 4))) = bf16b(acc[n][r] * inv);
        }
    }

    __syncthreads();   // all waves done reading K; P writes visible

    // ---- stage V (bf16 global, transposed layout) into KV ----
    #pragma unroll
    for (int i = 0; i < 8; ++i) {
        int idx = tid + i * 256;            // 0..2047
        int row = idx >> 5, kc = idx & 31;  // row = dv 0..63, kc = 16B chunk
        uint4 v = *reinterpret_cast<const uint4*>(
            VtG + ((size_t)t * DM + h * HEAD_ + row) * M_ + kc * 8);
        *reinterpret_cast<uint4*>(KV + ((row * 512 + kc * 16) ^ ((row & 7) << 4))) = v;
    }
    __syncthreads();

    // ---- PV: U[16 q x 64 dv] per wave ----
    f32x4 o[4] = {{0.f,0.f,0.f,0.f},{0.f,0.f,0.f,0.f},{0.f,0.f,0.f,0.f},{0.f,0.f,0.f,0.f}};
    #pragma unroll
    for (int ks = 0; ks < 8; ++ks) {
        int rp = wq * 16 + c;
        short8 aP = *reinterpret_cast<short8*>(
            Ps + ((rp * 512 + ks * 64 + g * 16) ^ ((rp & 7) << 4)));
        #pragma unroll
        for (int nv = 0; nv < 4; ++nv) {
            int rv = nv * 16 + c;
            short8 bV = *reinterpret_cast<short8*>(
                KV + ((rv * 512 + ks * 64 + g * 16) ^ ((rv & 7) << 4)));
            o[nv] = __builtin_amdgcn_mfma_f32_16x16x32_bf16(aP, bV, o[nv], 0, 0, 0);
        }
    }
    #pragma unroll
    for (int nv = 0; nv < 4; ++nv)
        #pragma unroll
        for (int r = 0; r < 4; ++r)
            U[(size_t)(t * HW_ + q0 + wq * 16 + g * 4 + r) * DM + h * HEAD_ + nv * 16 + c] =
                o[nv][r];
}

// ---------------------------------------------------------------------------
extern "C" void kernel_launch(void* const* d_in, const int* in_sizes, int n_in,
                              void* d_out, int out_size, void* d_ws, size_t ws_size,
                              hipStream_t stream) {
    const float* utt    = (const float*)d_in[0];
    const float* tracks = (const float*)d_in[1];
    const float* fpos   = (const float*)d_in[2];
    const float* fpe    = (const float*)d_in[3];
    const float* tpe    = (const float*)d_in[4];
    const float* Wq     = (const float*)d_in[5];
    const float* Wk     = (const float*)d_in[6];
    const float* Wv     = (const float*)d_in[7];
    const float* Wo     = (const float*)d_in[8];
    const float* qgamma = (const float*)d_in[9];
    const float* kgamma = (const float*)d_in[10];
    float* out = (float*)d_out;

    char* ws = (char*)d_ws;
    float*          Qf = (float*)(ws);                   // 33554432 B
    float*          Kf = (float*)(ws + 33554432);        //  8388608 B
    float*          Vf = (float*)(ws + 41943040);        //  8388608 B
    float*          U  = (float*)(ws + 50331648);        // 33554432 B
    unsigned short* Vt = (unsigned short*)(ws + 83886080); // 4194304 B

    // Projections (f32)
    gemm_xwt<<<dim3(8, 256), 256, 0, stream>>>(fpe, Wq, Qf);
    gemm_xwt<<<dim3(8, 64),  256, 0, stream>>>(tpe, Wk, Kf);
    gemm_xwt<<<dim3(8, 64),  256, 0, stream>>>(utt, Wv, Vf);

    // QK LayerNorm in-place (f32)
    ln_rows<<<4096, 256, 0, stream>>>(Qf, qgamma, 16384);
    ln_rows<<<1024, 256, 0, stream>>>(Kf, kgamma, 4096);

    // V transpose + cast to bf16 [T][dv][key]
    vtrans<<<dim3(8, 4, 16), 256, 0, stream>>>(Vf, Vt);

    // MFMA attention
    attn_mfma<<<dim3(16, 8, 16), 256, 0, stream>>>(Qf, Kf, Vt, tracks, fpos, U);

    // Out projection (f32)
    gemm_xwt<<<dim3(8, 256), 256, 0, stream>>>(U, Wo, out);
}

// Round 4
// 155.433 us; speedup vs baseline: 8.3798x; 3.1703x over previous
//
#include <hip/hip_runtime.h>

#define T_    16
#define M_    256
#define HW_   1024
#define DM    512
#define H_    8
#define HEAD_ 64

typedef __attribute__((ext_vector_type(8))) short short8;
typedef __attribute__((ext_vector_type(4))) float f32x4;

__device__ __forceinline__ unsigned short bf16b(float x) {
    unsigned u = __float_as_uint(x);
    unsigned r = (u + 0x7FFFu + ((u >> 16) & 1u)) >> 16;
    return (unsigned short)r;
}

// ---------------------------------------------------------------------------
// C[R x 512] = X[R x 512] @ W[512 x 512]^T  via bf16 MFMA (inline f32->bf16).
// Tile 128x128, BK=64, 256 threads = 4 waves, wave owns 64x64 (4x4 frags).
// ---------------------------------------------------------------------------
__global__ __launch_bounds__(256) void gemm_mfma(const float* __restrict__ X,
                                                 const float* __restrict__ W,
                                                 float* __restrict__ C) {
    __shared__ __align__(16) unsigned char smem[32768];
    unsigned char* As = smem;           // [128 r][64 k] bf16, swizzled
    unsigned char* Bs = smem + 16384;   // [128 c][64 k] bf16, swizzled

    const int tid = threadIdx.x;
    const int r0 = blockIdx.y * 128;
    const int c0 = blockIdx.x * 128;

    const int l  = tid & 63;
    const int wid = tid >> 6;
    const int wr = wid >> 1, wc = wid & 1;
    const int g = l >> 4;      // 0..3 (k-subchunk)
    const int c = l & 15;      // 0..15

    f32x4 acc[4][4] = {};

    for (int k0 = 0; k0 < DM; k0 += 64) {
        // ---- stage A and B tiles (f32 -> bf16, swizzled) ----
        #pragma unroll
        for (int i = 0; i < 4; ++i) {
            int idx = tid + i * 256;        // 0..1023
            int row = idx >> 3, dc = idx & 7;
            const unsigned off = (unsigned)((row * 128 + dc * 16) ^ ((row & 7) << 4));
            {
                const float* s = X + (size_t)(r0 + row) * DM + k0 + dc * 8;
                float4 a = *reinterpret_cast<const float4*>(s);
                float4 b = *reinterpret_cast<const float4*>(s + 4);
                short8 v;
                v[0] = bf16b(a.x); v[1] = bf16b(a.y); v[2] = bf16b(a.z); v[3] = bf16b(a.w);
                v[4] = bf16b(b.x); v[5] = bf16b(b.y); v[6] = bf16b(b.z); v[7] = bf16b(b.w);
                *reinterpret_cast<short8*>(As + off) = v;
            }
            {
                const float* s = W + (size_t)(c0 + row) * DM + k0 + dc * 8;
                float4 a = *reinterpret_cast<const float4*>(s);
                float4 b = *reinterpret_cast<const float4*>(s + 4);
                short8 v;
                v[0] = bf16b(a.x); v[1] = bf16b(a.y); v[2] = bf16b(a.z); v[3] = bf16b(a.w);
                v[4] = bf16b(b.x); v[5] = bf16b(b.y); v[6] = bf16b(b.z); v[7] = bf16b(b.w);
                *reinterpret_cast<short8*>(Bs + off) = v;
            }
        }
        __syncthreads();

        // ---- MFMA: 2 k-chunks of 32 ----
        #pragma unroll
        for (int ks = 0; ks < 2; ++ks) {
            short8 af[4], bfr[4];
            #pragma unroll
            for (int m = 0; m < 4; ++m) {
                int rq = wr * 64 + m * 16 + c;
                af[m] = *reinterpret_cast<short8*>(
                    As + ((rq * 128 + ks * 64 + g * 16) ^ ((rq & 7) << 4)));
            }
            #pragma unroll
            for (int n = 0; n < 4; ++n) {
                int rn = wc * 64 + n * 16 + c;
                bfr[n] = *reinterpret_cast<short8*>(
                    Bs + ((rn * 128 + ks * 64 + g * 16) ^ ((rn & 7) << 4)));
            }
            #pragma unroll
            for (int m = 0; m < 4; ++m)
                #pragma unroll
                for (int n = 0; n < 4; ++n)
                    acc[m][n] = __builtin_amdgcn_mfma_f32_16x16x32_bf16(
                        af[m], bfr[n], acc[m][n], 0, 0, 0);
        }
        __syncthreads();
    }

    // ---- epilogue: C[row = wr*64+m*16+g*4+r][col = wc*64+n*16+c] ----
    #pragma unroll
    for (int m = 0; m < 4; ++m)
        #pragma unroll
        for (int n = 0; n < 4; ++n)
            #pragma unroll
            for (int r = 0; r < 4; ++r)
                C[(size_t)(r0 + wr * 64 + m * 16 + g * 4 + r) * DM +
                  c0 + wc * 64 + n * 16 + c] = acc[m][n][r];
}

// ---------------------------------------------------------------------------
// In-place f32 LayerNorm (no bias), one wave per 512-row.
// ---------------------------------------------------------------------------
__global__ __launch_bounds__(256) void ln_rows(float* __restrict__ X,
                                               const float* __restrict__ gamma,
                                               int nrows) {
    const int wave = threadIdx.x / 64;
    const int lane = threadIdx.x % 64;
    const int row  = blockIdx.x * 4 + wave;
    if (row >= nrows) return;

    float4 v0 = *reinterpret_cast<const float4*>(&X[(size_t)row * DM + lane * 8]);
    float4 v1 = *reinterpret_cast<const float4*>(&X[(size_t)row * DM + lane * 8 + 4]);
    float x[8] = {v0.x, v0.y, v0.z, v0.w, v1.x, v1.y, v1.z, v1.w};

    float s = 0.f;
    #pragma unroll
    for (int i = 0; i < 8; ++i) s += x[i];
    #pragma unroll
    for (int m = 1; m < 64; m <<= 1) s += __shfl_xor(s, m, 64);
    const float mu = s * (1.0f / 512.0f);

    float vs = 0.f;
    #pragma unroll
    for (int i = 0; i < 8; ++i) { float d = x[i] - mu; vs += d * d; }
    #pragma unroll
    for (int m = 1; m < 64; m <<= 1) vs += __shfl_xor(vs, m, 64);
    const float rs = rsqrtf(vs * (1.0f / 512.0f) + 1e-6f);

    float4 g0 = *reinterpret_cast<const float4*>(&gamma[lane * 8]);
    float4 g1 = *reinterpret_cast<const float4*>(&gamma[lane * 8 + 4]);
    float g[8] = {g0.x, g0.y, g0.z, g0.w, g1.x, g1.y, g1.z, g1.w};

    float y[8];
    #pragma unroll
    for (int i = 0; i < 8; ++i) y[i] = (x[i] - mu) * rs * g[i];
    *reinterpret_cast<float4*>(&X[(size_t)row * DM + lane * 8]) =
        make_float4(y[0], y[1], y[2], y[3]);
    *reinterpret_cast<float4*>(&X[(size_t)row * DM + lane * 8 + 4]) =
        make_float4(y[4], y[5], y[6], y[7]);
}

// ---------------------------------------------------------------------------
// V [T*M][512] f32  ->  Vt [T][512 dv][256 key] bf16 (transpose + cast)
// ---------------------------------------------------------------------------
__global__ __launch_bounds__(256) void vtrans(const float* __restrict__ V,
                                              unsigned short* __restrict__ Vt) {
    const int t = blockIdx.z, kt = blockIdx.y, dt = blockIdx.x;
    __shared__ float tile[64][65];
    const int tid = threadIdx.x;

    #pragma unroll
    for (int i = 0; i < 4; ++i) {
        int idx = tid + i * 256;           // 0..1023
        int r = idx >> 4, c4 = idx & 15;
        float4 v = *reinterpret_cast<const float4*>(
            &V[(size_t)(t * M_ + kt * 64 + r) * DM + dt * 64 + c4 * 4]);
        tile[r][c4 * 4 + 0] = v.x;
        tile[r][c4 * 4 + 1] = v.y;
        tile[r][c4 * 4 + 2] = v.z;
        tile[r][c4 * 4 + 3] = v.w;
    }
    __syncthreads();
    #pragma unroll
    for (int i = 0; i < 4; ++i) {
        int idx = tid + i * 256;
        int r = idx >> 4, c4 = idx & 15;
        ushort4 o;
        o.x = bf16b(tile[c4 * 4 + 0][r]);
        o.y = bf16b(tile[c4 * 4 + 1][r]);
        o.z = bf16b(tile[c4 * 4 + 2][r]);
        o.w = bf16b(tile[c4 * 4 + 3][r]);
        *reinterpret_cast<ushort4*>(
            &Vt[((size_t)t * DM + dt * 64 + r) * M_ + kt * 64 + c4 * 4]) = o;
    }
}

// ---------------------------------------------------------------------------
// MFMA attention. Block = (qtile=64, h, t), 4 waves, wave owns 16 q-rows.
// ---------------------------------------------------------------------------
__global__ __launch_bounds__(256) void attn_mfma(const float* __restrict__ Qf,
                                                 const float* __restrict__ Kf,
                                                 const unsigned short* __restrict__ VtG,
                                                 const float* __restrict__ tracks,
                                                 const float* __restrict__ fpos,
                                                 float* __restrict__ U) {
    const int t  = blockIdx.z;
    const int h  = blockIdx.y;
    const int q0 = blockIdx.x * 64;
    const int tid = threadIdx.x;

    __shared__ __align__(16) unsigned char smem[76288];
    unsigned char* Qs = smem;              // [64 q ][64 d ] bf16 swz
    unsigned char* KV = smem + 8192;       // K:[256 k][64 d] / V:[64 dv][256 k]
    unsigned char* Ps = smem + 40960;      // [64 q ][256 k] bf16 swz
    float* trk = (float*)(smem + 73728);
    float* fps = (float*)(smem + 75776);

    #pragma unroll
    for (int i = 0; i < 2; ++i) {
        int idx = tid + i * 256;
        int row = idx >> 3, dc = idx & 7;
        const float* src = Qf + (size_t)(t * HW_ + q0 + row) * DM + h * HEAD_ + dc * 8;
        float4 a = *reinterpret_cast<const float4*>(src);
        float4 b = *reinterpret_cast<const float4*>(src + 4);
        short8 v;
        v[0] = bf16b(a.x); v[1] = bf16b(a.y); v[2] = bf16b(a.z); v[3] = bf16b(a.w);
        v[4] = bf16b(b.x); v[5] = bf16b(b.y); v[6] = bf16b(b.z); v[7] = bf16b(b.w);
        *reinterpret_cast<short8*>(Qs + ((row * 128 + dc * 16) ^ ((row & 7) << 4))) = v;
    }
    #pragma unroll
    for (int i = 0; i < 8; ++i) {
        int idx = tid + i * 256;
        int row = idx >> 3, dc = idx & 7;
        const float* src = Kf + (size_t)(t * M_ + row) * DM + h * HEAD_ + dc * 8;
        float4 a = *reinterpret_cast<const float4*>(src);
        float4 b = *reinterpret_cast<const float4*>(src + 4);
        short8 v;
        v[0] = bf16b(a.x); v[1] = bf16b(a.y); v[2] = bf16b(a.z); v[3] = bf16b(a.w);
        v[4] = bf16b(b.x); v[5] = bf16b(b.y); v[6] = bf16b(b.z); v[7] = bf16b(b.w);
        *reinterpret_cast<short8*>(KV + ((row * 128 + dc * 16) ^ ((row & 7) << 4))) = v;
    }
    trk[tid]       = tracks[(size_t)t * M_ * 2 + tid];
    trk[tid + 256] = tracks[(size_t)t * M_ * 2 + tid + 256];
    if (tid < 128) fps[tid] = fpos[(size_t)q0 * 2 + tid];
    __syncthreads();

    const int l = tid & 63;
    const int wq = tid >> 6;
    const int g = l >> 4;
    const int c = l & 15;

    const int rq = wq * 16 + c;
    short8 aQ0 = *reinterpret_cast<short8*>(Qs + ((rq * 128 +  0 + g * 16) ^ ((rq & 7) << 4)));
    short8 aQ1 = *reinterpret_cast<short8*>(Qs + ((rq * 128 + 64 + g * 16) ^ ((rq & 7) << 4)));

    f32x4 acc[16];
    #pragma unroll
    for (int n = 0; n < 16; ++n) {
        int rk = n * 16 + c;
        short8 b0 = *reinterpret_cast<short8*>(KV + ((rk * 128 +  0 + g * 16) ^ ((rk & 7) << 4)));
        short8 b1 = *reinterpret_cast<short8*>(KV + ((rk * 128 + 64 + g * 16) ^ ((rk & 7) << 4)));
        f32x4 z = {0.f, 0.f, 0.f, 0.f};
        z = __builtin_amdgcn_mfma_f32_16x16x32_bf16(aQ0, b0, z, 0, 0, 0);
        z = __builtin_amdgcn_mfma_f32_16x16x32_bf16(aQ1, b1, z, 0, 0, 0);
        acc[n] = z;
    }

    float fx[4], fy[4];
    #pragma unroll
    for (int r = 0; r < 4; ++r) {
        int ql = wq * 16 + g * 4 + r;
        fx[r] = fps[ql * 2]; fy[r] = fps[ql * 2 + 1];
    }
    #pragma unroll
    for (int n = 0; n < 16; ++n) {
        float2 tk = *reinterpret_cast<float2*>(&trk[(n * 16 + c) * 2]);
        #pragma unroll
        for (int r = 0; r < 4; ++r) {
            float dx = fx[r] - tk.x, dy = fy[r] - tk.y;
            acc[n][r] = acc[n][r] * 0.125f - 2.0f * (dx * dx + dy * dy);
        }
    }

    #pragma unroll
    for (int r = 0; r < 4; ++r) {
        float m = acc[0][r];
        #pragma unroll
        for (int n = 1; n < 16; ++n) m = fmaxf(m, acc[n][r]);
        #pragma unroll
        for (int b = 1; b < 16; b <<= 1) m = fmaxf(m, __shfl_xor(m, b, 64));
        float s = 0.f;
        #pragma unroll
        for (int n = 0; n < 16; ++n) { float e = __expf(acc[n][r] - m); acc[n][r] = e; s += e; }
        #pragma unroll
        for (int b = 1; b < 16; b <<= 1) s += __shfl_xor(s, b, 64);
        const float inv = 1.0f / s;
        const int row = wq * 16 + g * 4 + r;
        #pragma unroll
        for (int n = 0; n < 16; ++n) {
            int key = n * 16 + c;
            *reinterpret_cast<unsigned short*>(
                Ps + ((row * 512 + key * 2) ^ ((row & 7) << 4))) = bf16b(acc[n][r] * inv);
        }
    }

    __syncthreads();

    #pragma unroll
    for (int i = 0; i < 8; ++i) {
        int idx = tid + i * 256;
        int row = idx >> 5, kc = idx & 31;
        uint4 v = *reinterpret_cast<const uint4*>(
            VtG + ((size_t)t * DM + h * HEAD_ + row) * M_ + kc * 8);
        *reinterpret_cast<uint4*>(KV + ((row * 512 + kc * 16) ^ ((row & 7) << 4))) = v;
    }
    __syncthreads();

    f32x4 o[4] = {{0.f,0.f,0.f,0.f},{0.f,0.f,0.f,0.f},{0.f,0.f,0.f,0.f},{0.f,0.f,0.f,0.f}};
    #pragma unroll
    for (int ks = 0; ks < 8; ++ks) {
        int rp = wq * 16 + c;
        short8 aP = *reinterpret_cast<short8*>(
            Ps + ((rp * 512 + ks * 64 + g * 16) ^ ((rp & 7) << 4)));
        #pragma unroll
        for (int nv = 0; nv < 4; ++nv) {
            int rv = nv * 16 + c;
            short8 bV = *reinterpret_cast<short8*>(
                KV + ((rv * 512 + ks * 64 + g * 16) ^ ((rv & 7) << 4)));
            o[nv] = __builtin_amdgcn_mfma_f32_16x16x32_bf16(aP, bV, o[nv], 0, 0, 0);
        }
    }
    #pragma unroll
    for (int nv = 0; nv < 4; ++nv)
        #pragma unroll
        for (int r = 0; r < 4; ++r)
            U[(size_t)(t * HW_ + q0 + wq * 16 + g * 4 + r) * DM + h * HEAD_ + nv * 16 + c] =
                o[nv][r];
}

// ---------------------------------------------------------------------------
extern "C" void kernel_launch(void* const* d_in, const int* in_sizes, int n_in,
                              void* d_out, int out_size, void* d_ws, size_t ws_size,
                              hipStream_t stream) {
    const float* utt    = (const float*)d_in[0];
    const float* tracks = (const float*)d_in[1];
    const float* fpos   = (const float*)d_in[2];
    const float* fpe    = (const float*)d_in[3];
    const float* tpe    = (const float*)d_in[4];
    const float* Wq     = (const float*)d_in[5];
    const float* Wk     = (const float*)d_in[6];
    const float* Wv     = (const float*)d_in[7];
    const float* Wo     = (const float*)d_in[8];
    const float* qgamma = (const float*)d_in[9];
    const float* kgamma = (const float*)d_in[10];
    float* out = (float*)d_out;

    char* ws = (char*)d_ws;
    float*          Qf = (float*)(ws);                     // 33554432 B
    float*          Kf = (float*)(ws + 33554432);          //  8388608 B
    float*          Vf = (float*)(ws + 41943040);          //  8388608 B
    float*          U  = (float*)(ws + 50331648);          // 33554432 B
    unsigned short* Vt = (unsigned short*)(ws + 83886080); //  4194304 B

    // Projections (bf16 MFMA)
    gemm_mfma<<<dim3(4, 128), 256, 0, stream>>>(fpe, Wq, Qf);
    gemm_mfma<<<dim3(4, 32),  256, 0, stream>>>(tpe, Wk, Kf);
    gemm_mfma<<<dim3(4, 32),  256, 0, stream>>>(utt, Wv, Vf);

    // QK LayerNorm in-place (f32)
    ln_rows<<<4096, 256, 0, stream>>>(Qf, qgamma, 16384);
    ln_rows<<<1024, 256, 0, stream>>>(Kf, kgamma, 4096);

    // V transpose + cast to bf16 [T][dv][key]
    vtrans<<<dim3(8, 4, 16), 256, 0, stream>>>(Vf, Vt);

    // MFMA attention
    attn_mfma<<<dim3(16, 8, 16), 256, 0, stream>>>(Qf, Kf, Vt, tracks, fpos, U);

    // Out projection (bf16 MFMA)
    gemm_mfma<<<dim3(4, 128), 256, 0, stream>>>(U, Wo, out);
}

// Round 5
// 134.761 us; speedup vs baseline: 9.6652x; 1.1534x over previous
//
#include <hip/hip_runtime.h>

#define T_    16
#define M_    256
#define HW_   1024
#define DM    512
#define H_    8
#define HEAD_ 64

typedef __attribute__((ext_vector_type(8))) short short8;
typedef __attribute__((ext_vector_type(4))) float f32x4;

__device__ __forceinline__ unsigned short bf16b(float x) {
    unsigned u = __float_as_uint(x);
    unsigned r = (u + 0x7FFFu + ((u >> 16) & 1u)) >> 16;
    return (unsigned short)r;
}

// ---------------------------------------------------------------------------
// C[R x 512] = X[R x 512] @ W[512 x 512]^T  via bf16 MFMA, X in f32.
// ---------------------------------------------------------------------------
__global__ __launch_bounds__(256) void gemm_mfma(const float* __restrict__ X,
                                                 const float* __restrict__ W,
                                                 float* __restrict__ C) {
    __shared__ __align__(16) unsigned char smem[32768];
    unsigned char* As = smem;
    unsigned char* Bs = smem + 16384;

    const int tid = threadIdx.x;
    const int r0 = blockIdx.y * 128;
    const int c0 = blockIdx.x * 128;

    const int l  = tid & 63;
    const int wid = tid >> 6;
    const int wr = wid >> 1, wc = wid & 1;
    const int g = l >> 4;
    const int c = l & 15;

    f32x4 acc[4][4] = {};

    for (int k0 = 0; k0 < DM; k0 += 64) {
        #pragma unroll
        for (int i = 0; i < 4; ++i) {
            int idx = tid + i * 256;
            int row = idx >> 3, dc = idx & 7;
            const unsigned off = (unsigned)((row * 128 + dc * 16) ^ ((row & 7) << 4));
            {
                const float* s = X + (size_t)(r0 + row) * DM + k0 + dc * 8;
                float4 a = *reinterpret_cast<const float4*>(s);
                float4 b = *reinterpret_cast<const float4*>(s + 4);
                short8 v;
                v[0] = bf16b(a.x); v[1] = bf16b(a.y); v[2] = bf16b(a.z); v[3] = bf16b(a.w);
                v[4] = bf16b(b.x); v[5] = bf16b(b.y); v[6] = bf16b(b.z); v[7] = bf16b(b.w);
                *reinterpret_cast<short8*>(As + off) = v;
            }
            {
                const float* s = W + (size_t)(c0 + row) * DM + k0 + dc * 8;
                float4 a = *reinterpret_cast<const float4*>(s);
                float4 b = *reinterpret_cast<const float4*>(s + 4);
                short8 v;
                v[0] = bf16b(a.x); v[1] = bf16b(a.y); v[2] = bf16b(a.z); v[3] = bf16b(a.w);
                v[4] = bf16b(b.x); v[5] = bf16b(b.y); v[6] = bf16b(b.z); v[7] = bf16b(b.w);
                *reinterpret_cast<short8*>(Bs + off) = v;
            }
        }
        __syncthreads();

        #pragma unroll
        for (int ks = 0; ks < 2; ++ks) {
            short8 af[4], bfr[4];
            #pragma unroll
            for (int m = 0; m < 4; ++m) {
                int rq = wr * 64 + m * 16 + c;
                af[m] = *reinterpret_cast<short8*>(
                    As + ((rq * 128 + ks * 64 + g * 16) ^ ((rq & 7) << 4)));
            }
            #pragma unroll
            for (int n = 0; n < 4; ++n) {
                int rn = wc * 64 + n * 16 + c;
                bfr[n] = *reinterpret_cast<short8*>(
                    Bs + ((rn * 128 + ks * 64 + g * 16) ^ ((rn & 7) << 4)));
            }
            #pragma unroll
            for (int m = 0; m < 4; ++m)
                #pragma unroll
                for (int n = 0; n < 4; ++n)
                    acc[m][n] = __builtin_amdgcn_mfma_f32_16x16x32_bf16(
                        af[m], bfr[n], acc[m][n], 0, 0, 0);
        }
        __syncthreads();
    }

    #pragma unroll
    for (int m = 0; m < 4; ++m)
        #pragma unroll
        for (int n = 0; n < 4; ++n)
            #pragma unroll
            for (int r = 0; r < 4; ++r)
                C[(size_t)(r0 + wr * 64 + m * 16 + g * 4 + r) * DM +
                  c0 + wc * 64 + n * 16 + c] = acc[m][n][r];
}

// ---------------------------------------------------------------------------
// Same GEMM but X is bf16 (used for out-projection on U).
// ---------------------------------------------------------------------------
__global__ __launch_bounds__(256) void gemm_mfma_bx(const unsigned short* __restrict__ X,
                                                    const float* __restrict__ W,
                                                    float* __restrict__ C) {
    __shared__ __align__(16) unsigned char smem[32768];
    unsigned char* As = smem;
    unsigned char* Bs = smem + 16384;

    const int tid = threadIdx.x;
    const int r0 = blockIdx.y * 128;
    const int c0 = blockIdx.x * 128;

    const int l  = tid & 63;
    const int wid = tid >> 6;
    const int wr = wid >> 1, wc = wid & 1;
    const int g = l >> 4;
    const int c = l & 15;

    f32x4 acc[4][4] = {};

    for (int k0 = 0; k0 < DM; k0 += 64) {
        #pragma unroll
        for (int i = 0; i < 4; ++i) {
            int idx = tid + i * 256;
            int row = idx >> 3, dc = idx & 7;
            const unsigned off = (unsigned)((row * 128 + dc * 16) ^ ((row & 7) << 4));
            {
                uint4 v = *reinterpret_cast<const uint4*>(
                    X + (size_t)(r0 + row) * DM + k0 + dc * 8);
                *reinterpret_cast<uint4*>(As + off) = v;
            }
            {
                const float* s = W + (size_t)(c0 + row) * DM + k0 + dc * 8;
                float4 a = *reinterpret_cast<const float4*>(s);
                float4 b = *reinterpret_cast<const float4*>(s + 4);
                short8 v;
                v[0] = bf16b(a.x); v[1] = bf16b(a.y); v[2] = bf16b(a.z); v[3] = bf16b(a.w);
                v[4] = bf16b(b.x); v[5] = bf16b(b.y); v[6] = bf16b(b.z); v[7] = bf16b(b.w);
                *reinterpret_cast<short8*>(Bs + off) = v;
            }
        }
        __syncthreads();

        #pragma unroll
        for (int ks = 0; ks < 2; ++ks) {
            short8 af[4], bfr[4];
            #pragma unroll
            for (int m = 0; m < 4; ++m) {
                int rq = wr * 64 + m * 16 + c;
                af[m] = *reinterpret_cast<short8*>(
                    As + ((rq * 128 + ks * 64 + g * 16) ^ ((rq & 7) << 4)));
            }
            #pragma unroll
            for (int n = 0; n < 4; ++n) {
                int rn = wc * 64 + n * 16 + c;
                bfr[n] = *reinterpret_cast<short8*>(
                    Bs + ((rn * 128 + ks * 64 + g * 16) ^ ((rn & 7) << 4)));
            }
            #pragma unroll
            for (int m = 0; m < 4; ++m)
                #pragma unroll
                for (int n = 0; n < 4; ++n)
                    acc[m][n] = __builtin_amdgcn_mfma_f32_16x16x32_bf16(
                        af[m], bfr[n], acc[m][n], 0, 0, 0);
        }
        __syncthreads();
    }

    #pragma unroll
    for (int m = 0; m < 4; ++m)
        #pragma unroll
        for (int n = 0; n < 4; ++n)
            #pragma unroll
            for (int r = 0; r < 4; ++r)
                C[(size_t)(r0 + wr * 64 + m * 16 + g * 4 + r) * DM +
                  c0 + wc * 64 + n * 16 + c] = acc[m][n][r];
}

// ---------------------------------------------------------------------------
// LayerNorm (no bias) f32 in -> bf16 out, one wave per 512-row.
// ---------------------------------------------------------------------------
__global__ __launch_bounds__(256) void ln_rows_bf16(const float* __restrict__ X,
                                                    const float* __restrict__ gamma,
                                                    unsigned short* __restrict__ Y,
                                                    int nrows) {
    const int wave = threadIdx.x / 64;
    const int lane = threadIdx.x % 64;
    const int row  = blockIdx.x * 4 + wave;
    if (row >= nrows) return;

    float4 v0 = *reinterpret_cast<const float4*>(&X[(size_t)row * DM + lane * 8]);
    float4 v1 = *reinterpret_cast<const float4*>(&X[(size_t)row * DM + lane * 8 + 4]);
    float x[8] = {v0.x, v0.y, v0.z, v0.w, v1.x, v1.y, v1.z, v1.w};

    float s = 0.f;
    #pragma unroll
    for (int i = 0; i < 8; ++i) s += x[i];
    #pragma unroll
    for (int m = 1; m < 64; m <<= 1) s += __shfl_xor(s, m, 64);
    const float mu = s * (1.0f / 512.0f);

    float vs = 0.f;
    #pragma unroll
    for (int i = 0; i < 8; ++i) { float d = x[i] - mu; vs += d * d; }
    #pragma unroll
    for (int m = 1; m < 64; m <<= 1) vs += __shfl_xor(vs, m, 64);
    const float rs = rsqrtf(vs * (1.0f / 512.0f) + 1e-6f);

    float4 g0 = *reinterpret_cast<const float4*>(&gamma[lane * 8]);
    float4 g1 = *reinterpret_cast<const float4*>(&gamma[lane * 8 + 4]);
    float g[8] = {g0.x, g0.y, g0.z, g0.w, g1.x, g1.y, g1.z, g1.w};

    short8 yv;
    #pragma unroll
    for (int i = 0; i < 8; ++i) yv[i] = (short)bf16b((x[i] - mu) * rs * g[i]);
    *reinterpret_cast<short8*>(&Y[(size_t)row * DM + lane * 8]) = yv;
}

// ---------------------------------------------------------------------------
// V [T*M][512] f32  ->  Vt [T][512 dv][256 key] bf16 (transpose + cast)
// ---------------------------------------------------------------------------
__global__ __launch_bounds__(256) void vtrans(const float* __restrict__ V,
                                              unsigned short* __restrict__ Vt) {
    const int t = blockIdx.z, kt = blockIdx.y, dt = blockIdx.x;
    __shared__ float tile[64][65];
    const int tid = threadIdx.x;

    #pragma unroll
    for (int i = 0; i < 4; ++i) {
        int idx = tid + i * 256;
        int r = idx >> 4, c4 = idx & 15;
        float4 v = *reinterpret_cast<const float4*>(
            &V[(size_t)(t * M_ + kt * 64 + r) * DM + dt * 64 + c4 * 4]);
        tile[r][c4 * 4 + 0] = v.x;
        tile[r][c4 * 4 + 1] = v.y;
        tile[r][c4 * 4 + 2] = v.z;
        tile[r][c4 * 4 + 3] = v.w;
    }
    __syncthreads();
    #pragma unroll
    for (int i = 0; i < 4; ++i) {
        int idx = tid + i * 256;
        int r = idx >> 4, c4 = idx & 15;
        ushort4 o;
        o.x = bf16b(tile[c4 * 4 + 0][r]);
        o.y = bf16b(tile[c4 * 4 + 1][r]);
        o.z = bf16b(tile[c4 * 4 + 2][r]);
        o.w = bf16b(tile[c4 * 4 + 3][r]);
        *reinterpret_cast<ushort4*>(
            &Vt[((size_t)t * DM + dt * 64 + r) * M_ + kt * 64 + c4 * 4]) = o;
    }
}

// ---------------------------------------------------------------------------
// MFMA attention, transposed-scores + in-register P redistribution.
// Block = one (t, h, 64-q tile); 4 waves x 16 q-rows; LDS = K/V (shared) only.
// ---------------------------------------------------------------------------
__global__ __launch_bounds__(256, 4) void attn_mfma(const unsigned short* __restrict__ Qbf,
                                                    const unsigned short* __restrict__ Kbf,
                                                    const unsigned short* __restrict__ VtG,
                                                    const float* __restrict__ tracks,
                                                    const float* __restrict__ fpos,
                                                    unsigned short* __restrict__ Ubf) {
    // XCD-grouping swizzle: blocks sharing (t,h) land on one XCD (id = b%8).
    const int b   = blockIdx.x;
    const int xcd = b & 7;
    const int bi  = b >> 3;
    const int qt  = bi & 15;
    const int pp  = xcd + (bi >> 4) * 8;   // 0..127 = t*8 + h
    const int t   = pp >> 3;
    const int h   = pp & 7;
    const int q0  = qt * 64;
    const int tid = threadIdx.x;

    __shared__ __align__(16) unsigned char smem[32768 + 2048 + 512];
    unsigned char* KV = smem;                       // K [256k][64d] then V [64dv][256k], swz
    float* trk = (float*)(smem + 32768);            // 256 x {x,y}
    float* fps = (float*)(smem + 32768 + 2048);     // 64 x {x,y}

    // ---- stage K (bf16 16B copies, swizzled) + trk + fps ----
    #pragma unroll
    for (int it = 0; it < 8; ++it) {
        int idx = tid + it * 256;              // 0..2047
        int row = idx >> 3, j = idx & 7;
        uint4 v = *reinterpret_cast<const uint4*>(
            Kbf + (size_t)(t * M_ + row) * DM + h * HEAD_ + j * 8);
        *reinterpret_cast<uint4*>(KV + ((row * 128 + j * 16) ^ ((row & 7) << 4))) = v;
    }
    trk[tid]       = tracks[t * 512 + tid];
    trk[tid + 256] = tracks[t * 512 + 256 + tid];
    if (tid < 128) fps[tid] = fpos[q0 * 2 + tid];
    __syncthreads();

    const int l  = tid & 63;
    const int wq = tid >> 6;
    const int g  = l >> 4;     // 0..3
    const int c  = l & 15;     // 0..15

    // ---- Q B-fragments direct from global ----
    const unsigned short* qrow =
        Qbf + (size_t)(t * HW_ + q0 + wq * 16 + c) * DM + h * HEAD_;
    short8 bQ0 = *reinterpret_cast<const short8*>(qrow + g * 8);
    short8 bQ1 = *reinterpret_cast<const short8*>(qrow + 32 + g * 8);

    // ---- scores^T = mfma(K, Q): acc[n][r] = S[key=n*16+g*4+r][q=wq*16+c] ----
    f32x4 acc[16];
    #pragma unroll
    for (int n = 0; n < 16; ++n) {
        int rk = n * 16 + c;
        short8 a0 = *reinterpret_cast<short8*>(KV + ((rk * 128 + g * 16) ^ ((rk & 7) << 4)));
        short8 a1 = *reinterpret_cast<short8*>(KV + ((rk * 128 + 64 + g * 16) ^ ((rk & 7) << 4)));
        f32x4 z = {0.f, 0.f, 0.f, 0.f};
        z = __builtin_amdgcn_mfma_f32_16x16x32_bf16(a0, bQ0, z, 0, 0, 0);
        z = __builtin_amdgcn_mfma_f32_16x16x32_bf16(a1, bQ1, z, 0, 0, 0);
        acc[n] = z;
    }

    // ---- bias: q fixed per lane (=wq*16+c), keys n*16+g*4+r ----
    const float fx = fps[(wq * 16 + c) * 2];
    const float fy = fps[(wq * 16 + c) * 2 + 1];
    #pragma unroll
    for (int n = 0; n < 16; ++n) {
        float4 t01 = *reinterpret_cast<float4*>(&trk[(n * 16 + g * 4) * 2]);
        float4 t23 = *reinterpret_cast<float4*>(&trk[(n * 16 + g * 4) * 2 + 4]);
        float dx, dy;
        dx = fx - t01.x; dy = fy - t01.y;
        acc[n][0] = acc[n][0] * 0.125f - 2.0f * (dx * dx + dy * dy);
        dx = fx - t01.z; dy = fy - t01.w;
        acc[n][1] = acc[n][1] * 0.125f - 2.0f * (dx * dx + dy * dy);
        dx = fx - t23.x; dy = fy - t23.y;
        acc[n][2] = acc[n][2] * 0.125f - 2.0f * (dx * dx + dy * dy);
        dx = fx - t23.z; dy = fy - t23.w;
        acc[n][3] = acc[n][3] * 0.125f - 2.0f * (dx * dx + dy * dy);
    }

    // ---- softmax over 256 keys of q=wq*16+c: 64 in-lane + cross-g reduce ----
    float mx = -1e30f;
    #pragma unroll
    for (int n = 0; n < 16; ++n)
        mx = fmaxf(mx, fmaxf(fmaxf(acc[n][0], acc[n][1]), fmaxf(acc[n][2], acc[n][3])));
    mx = fmaxf(mx, __shfl_xor(mx, 16, 64));
    mx = fmaxf(mx, __shfl_xor(mx, 32, 64));
    float sum = 0.f;
    #pragma unroll
    for (int n = 0; n < 16; ++n)
        #pragma unroll
        for (int r = 0; r < 4; ++r) {
            float e = __expf(acc[n][r] - mx);
            acc[n][r] = e;
            sum += e;
        }
    sum += __shfl_xor(sum, 16, 64);
    sum += __shfl_xor(sum, 32, 64);
    const float inv = 1.0f / sum;

    // ---- pack P to bf16 pairs: pk[n][w] = keys n*16+g*4+{2w,2w+1} ----
    unsigned pk[16][2];
    #pragma unroll
    for (int n = 0; n < 16; ++n) {
        pk[n][0] = (unsigned)bf16b(acc[n][0] * inv) |
                   ((unsigned)bf16b(acc[n][1] * inv) << 16);
        pk[n][1] = (unsigned)bf16b(acc[n][2] * inv) |
                   ((unsigned)bf16b(acc[n][3] * inv) << 16);
    }

    __syncthreads();   // all waves done with K region -> safe to overwrite with V

    // ---- stage V [64 dv][256 key] bf16 swizzled (overlays K) ----
    #pragma unroll
    for (int it = 0; it < 8; ++it) {
        int idx = tid + it * 256;               // 0..2047
        int row = idx >> 5, kc = idx & 31;      // row = dv-local, kc = 16B chunk
        uint4 v = *reinterpret_cast<const uint4*>(
            VtG + ((size_t)t * DM + h * HEAD_ + row) * M_ + kc * 8);
        *reinterpret_cast<uint4*>(KV + ((row * 512 + kc * 16) ^ ((row & 7) << 4))) = v;
    }
    __syncthreads();

    // ---- PV: redistribute P to A-frag layout via intra-g-group shuffles ----
    f32x4 o[4] = {{0.f,0.f,0.f,0.f},{0.f,0.f,0.f,0.f},{0.f,0.f,0.f,0.f},{0.f,0.f,0.f,0.f}};
    #pragma unroll
    for (int ks = 0; ks < 8; ++ks) {
        unsigned wb[4];
        #pragma unroll
        for (int wt = 0; wt < 4; ++wt) {
            // target lane (g,c) word wt = pk[2ks+(g>>1)][wt&1] from lane (2(g&1)+(wt>>1), c)
            int src = ((l & 16) << 1) + (wt >> 1) * 16 + c;
            unsigned ve = (unsigned)__shfl((int)pk[2 * ks][wt & 1], src, 64);
            unsigned vo = (unsigned)__shfl((int)pk[2 * ks + 1][wt & 1], src, 64);
            wb[wt] = (g < 2) ? ve : vo;
        }
        uint4 uu = make_uint4(wb[0], wb[1], wb[2], wb[3]);
        short8 aP = *reinterpret_cast<short8*>(&uu);
        #pragma unroll
        for (int nv = 0; nv < 4; ++nv) {
            int rv = nv * 16 + c;
            short8 bV = *reinterpret_cast<short8*>(
                KV + ((rv * 512 + ks * 64 + g * 16) ^ ((rv & 7) << 4)));
            o[nv] = __builtin_amdgcn_mfma_f32_16x16x32_bf16(aP, bV, o[nv], 0, 0, 0);
        }
    }

    // ---- store U as bf16 ----
    #pragma unroll
    for (int nv = 0; nv < 4; ++nv)
        #pragma unroll
        for (int r = 0; r < 4; ++r)
            Ubf[(size_t)(t * HW_ + q0 + wq * 16 + g * 4 + r) * DM +
                h * HEAD_ + nv * 16 + c] = bf16b(o[nv][r]);
}

// ---------------------------------------------------------------------------
extern "C" void kernel_launch(void* const* d_in, const int* in_sizes, int n_in,
                              void* d_out, int out_size, void* d_ws, size_t ws_size,
                              hipStream_t stream) {
    const float* utt    = (const float*)d_in[0];
    const float* tracks = (const float*)d_in[1];
    const float* fpos   = (const float*)d_in[2];
    const float* fpe    = (const float*)d_in[3];
    const float* tpe    = (const float*)d_in[4];
    const float* Wq     = (const float*)d_in[5];
    const float* Wk     = (const float*)d_in[6];
    const float* Wv     = (const float*)d_in[7];
    const float* Wo     = (const float*)d_in[8];
    const float* qgamma = (const float*)d_in[9];
    const float* kgamma = (const float*)d_in[10];
    float* out = (float*)d_out;

    char* ws = (char*)d_ws;
    float*          Qf  = (float*)(ws);                       // [0, 33554432)
    float*          Kf  = (float*)(ws + 33554432);            // [33.5M, 41.9M)  dead after LN-K
    float*          Vf  = (float*)(ws + 41943040);            // [41.9M, 50.3M)  dead after vtrans
    unsigned short* Qbf = (unsigned short*)(ws + 33554432);   // overlays Kf+Vf (written after both dead)
    unsigned short* Ubf = (unsigned short*)(ws + 50331648);   // [50.3M, 67.1M)
    unsigned short* Vt  = (unsigned short*)(ws + 67108864);   // [67.1M, 71.3M)
    unsigned short* Kbf = (unsigned short*)(ws + 71303168);   // [71.3M, 75.5M)

    // Projections (bf16 MFMA, f32 inputs)
    gemm_mfma<<<dim3(4, 128), 256, 0, stream>>>(fpe, Wq, Qf);
    gemm_mfma<<<dim3(4, 32),  256, 0, stream>>>(tpe, Wk, Kf);
    gemm_mfma<<<dim3(4, 32),  256, 0, stream>>>(utt, Wv, Vf);

    // V transpose+cast (must precede LN-Q which overwrites Vf region)
    vtrans<<<dim3(8, 4, 16), 256, 0, stream>>>(Vf, Vt);

    // LayerNorm -> bf16 (K first: reads Kf before Qbf overwrites it)
    ln_rows_bf16<<<1024, 256, 0, stream>>>(Kf, kgamma, Kbf, 4096);
    ln_rows_bf16<<<4096, 256, 0, stream>>>(Qf, qgamma, Qbf, 16384);

    // Fused MFMA attention -> bf16 U
    attn_mfma<<<2048, 256, 0, stream>>>(Qbf, Kbf, Vt, tracks, fpos, Ubf);

    // Out projection (bf16 X)
    gemm_mfma_bx<<<dim3(4, 128), 256, 0, stream>>>(Ubf, Wo, out);
}

// Round 9
// 122.255 us; speedup vs baseline: 10.6539x; 1.1023x over previous
//
#include <hip/hip_runtime.h>

#define T_    16
#define M_    256
#define HW_   1024
#define DM    512
#define H_    8
#define HEAD_ 64
#define LOG2E 1.4426950408889634f

typedef __attribute__((ext_vector_type(8))) short short8;
typedef __attribute__((ext_vector_type(4))) float f32x4;

__device__ __forceinline__ unsigned cvtpk(float lo, float hi) {
    unsigned r;
    asm("v_cvt_pk_bf16_f32 %0, %1, %2" : "=v"(r) : "v"(lo), "v"(hi));
    return r;
}

__device__ __forceinline__ void gload16(const void* g, void* l) {
    __builtin_amdgcn_global_load_lds(
        (const __attribute__((address_space(1))) void*)g,
        (__attribute__((address_space(3))) void*)l, 16, 0, 0);
}

// ---------------------------------------------------------------------------
// W f32 [4 x 512 x 512] -> bf16 (one launch, y selects tensor)
// ---------------------------------------------------------------------------
__global__ __launch_bounds__(256) void cvtw(const float* __restrict__ W0,
                                            const float* __restrict__ W1,
                                            const float* __restrict__ W2,
                                            const float* __restrict__ W3,
                                            unsigned short* __restrict__ O) {
    const int y = blockIdx.y;
    const float* src = (y == 0) ? W0 : (y == 1) ? W1 : (y == 2) ? W2 : W3;
    const int base = (blockIdx.x * 256 + threadIdx.x) * 8;
    float4 a = *reinterpret_cast<const float4*>(src + base);
    float4 b = *reinterpret_cast<const float4*>(src + base + 4);
    uint4 v = make_uint4(cvtpk(a.x, a.y), cvtpk(a.z, a.w),
                         cvtpk(b.x, b.y), cvtpk(b.z, b.w));
    *reinterpret_cast<uint4*>(O + (size_t)y * 262144 + base) = v;
}

// ---------------------------------------------------------------------------
// C = X(f32) @ W(bf16)^T.  X staged via cvt_pk; W via global_load_lds with
// pre-swizzled source (linear LDS dest, swizzled read).  z selects operand set.
// ---------------------------------------------------------------------------
__global__ __launch_bounds__(256) void gemm_fw(const float* X0, const unsigned short* W0, float* C0,
                                               const float* X1, const unsigned short* W1, float* C1) {
    __shared__ __align__(16) unsigned char smem[32768];
    unsigned char* As = smem;
    unsigned char* Bs = smem + 16384;

    const int z = blockIdx.z;
    const float* X = z ? X1 : X0;
    const unsigned short* W = z ? W1 : W0;
    float* C = z ? C1 : C0;

    const int tid = threadIdx.x;
    const int r0 = blockIdx.y * 128;
    const int c0 = blockIdx.x * 128;

    const int l  = tid & 63;
    const int wid = tid >> 6;
    const int wr = wid >> 1, wc = wid & 1;
    const int g = l >> 4;
    const int c = l & 15;

    f32x4 acc[4][4] = {};

    for (int k0 = 0; k0 < DM; k0 += 64) {
        #pragma unroll
        for (int i = 0; i < 4; ++i) {
            int idx = tid + i * 256;
            int row = idx >> 3, dc = idx & 7;
            const unsigned off = (unsigned)((row * 128 + dc * 16) ^ ((row & 7) << 4));
            const float* s = X + (size_t)(r0 + row) * DM + k0 + dc * 8;
            float4 a = *reinterpret_cast<const float4*>(s);
            float4 b = *reinterpret_cast<const float4*>(s + 4);
            uint4 v = make_uint4(cvtpk(a.x, a.y), cvtpk(a.z, a.w),
                                 cvtpk(b.x, b.y), cvtpk(b.z, b.w));
            *reinterpret_cast<uint4*>(As + off) = v;
        }
        #pragma unroll
        for (int i = 0; i < 4; ++i) {
            int idx = tid + i * 256;
            int row = idx >> 3, jj = idx & 7;
            int j = jj ^ (row & 7);
            gload16(W + (size_t)(c0 + row) * DM + k0 + j * 8, Bs + idx * 16);
        }
        __syncthreads();

        #pragma unroll
        for (int ks = 0; ks < 2; ++ks) {
            short8 af[4], bfr[4];
            #pragma unroll
            for (int m = 0; m < 4; ++m) {
                int rq = wr * 64 + m * 16 + c;
                af[m] = *reinterpret_cast<short8*>(
                    As + ((rq * 128 + ks * 64 + g * 16) ^ ((rq & 7) << 4)));
            }
            #pragma unroll
            for (int n = 0; n < 4; ++n) {
                int rn = wc * 64 + n * 16 + c;
                bfr[n] = *reinterpret_cast<short8*>(
                    Bs + ((rn * 128 + ks * 64 + g * 16) ^ ((rn & 7) << 4)));
            }
            #pragma unroll
            for (int m = 0; m < 4; ++m)
                #pragma unroll
                for (int n = 0; n < 4; ++n)
                    acc[m][n] = __builtin_amdgcn_mfma_f32_16x16x32_bf16(
                        af[m], bfr[n], acc[m][n], 0, 0, 0);
        }
        __syncthreads();
    }

    #pragma unroll
    for (int m = 0; m < 4; ++m)
        #pragma unroll
        for (int n = 0; n < 4; ++n)
            #pragma unroll
            for (int r = 0; r < 4; ++r)
                C[(size_t)(r0 + wr * 64 + m * 16 + g * 4 + r) * DM +
                  c0 + wc * 64 + n * 16 + c] = acc[m][n][r];
}

// ---------------------------------------------------------------------------
// C = X(bf16) @ W(bf16)^T — both operands via global_load_lds. (out-proj)
// ---------------------------------------------------------------------------
__global__ __launch_bounds__(256) void gemm_bb(const unsigned short* __restrict__ X,
                                               const unsigned short* __restrict__ W,
                                               float* __restrict__ C) {
    __shared__ __align__(16) unsigned char smem[32768];
    unsigned char* As = smem;
    unsigned char* Bs = smem + 16384;

    const int tid = threadIdx.x;
    const int r0 = blockIdx.y * 128;
    const int c0 = blockIdx.x * 128;

    const int l  = tid & 63;
    const int wid = tid >> 6;
    const int wr = wid >> 1, wc = wid & 1;
    const int g = l >> 4;
    const int c = l & 15;

    f32x4 acc[4][4] = {};

    for (int k0 = 0; k0 < DM; k0 += 64) {
        #pragma unroll
        for (int i = 0; i < 4; ++i) {
            int idx = tid + i * 256;
            int row = idx >> 3, jj = idx & 7;
            int j = jj ^ (row & 7);
            gload16(X + (size_t)(r0 + row) * DM + k0 + j * 8, As + idx * 16);
            gload16(W + (size_t)(c0 + row) * DM + k0 + j * 8, Bs + idx * 16);
        }
        __syncthreads();

        #pragma unroll
        for (int ks = 0; ks < 2; ++ks) {
            short8 af[4], bfr[4];
            #pragma unroll
            for (int m = 0; m < 4; ++m) {
                int rq = wr * 64 + m * 16 + c;
                af[m] = *reinterpret_cast<short8*>(
                    As + ((rq * 128 + ks * 64 + g * 16) ^ ((rq & 7) << 4)));
            }
            #pragma unroll
            for (int n = 0; n < 4; ++n) {
                int rn = wc * 64 + n * 16 + c;
                bfr[n] = *reinterpret_cast<short8*>(
                    Bs + ((rn * 128 + ks * 64 + g * 16) ^ ((rn & 7) << 4)));
            }
            #pragma unroll
            for (int m = 0; m < 4; ++m)
                #pragma unroll
                for (int n = 0; n < 4; ++n)
                    acc[m][n] = __builtin_amdgcn_mfma_f32_16x16x32_bf16(
                        af[m], bfr[n], acc[m][n], 0, 0, 0);
        }
        __syncthreads();
    }

    #pragma unroll
    for (int m = 0; m < 4; ++m)
        #pragma unroll
        for (int n = 0; n < 4; ++n)
            #pragma unroll
            for (int r = 0; r < 4; ++r)
                C[(size_t)(r0 + wr * 64 + m * 16 + g * 4 + r) * DM +
                  c0 + wc * 64 + n * 16 + c] = acc[m][n][r];
}

// ---------------------------------------------------------------------------
// LayerNorm f32 -> bf16 with folded output scale (Q gets 0.125*log2e).
// ---------------------------------------------------------------------------
__global__ __launch_bounds__(256) void ln_rows_bf16(const float* __restrict__ X,
                                                    const float* __restrict__ gamma,
                                                    unsigned short* __restrict__ Y,
                                                    int nrows, float sc) {
    const int wave = threadIdx.x / 64;
    const int lane = threadIdx.x % 64;
    const int row  = blockIdx.x * 4 + wave;
    if (row >= nrows) return;

    float4 v0 = *reinterpret_cast<const float4*>(&X[(size_t)row * DM + lane * 8]);
    float4 v1 = *reinterpret_cast<const float4*>(&X[(size_t)row * DM + lane * 8 + 4]);
    float x[8] = {v0.x, v0.y, v0.z, v0.w, v1.x, v1.y, v1.z, v1.w};

    float s = 0.f;
    #pragma unroll
    for (int i = 0; i < 8; ++i) s += x[i];
    #pragma unroll
    for (int m = 1; m < 64; m <<= 1) s += __shfl_xor(s, m, 64);
    const float mu = s * (1.0f / 512.0f);

    float vs = 0.f;
    #pragma unroll
    for (int i = 0; i < 8; ++i) { float d = x[i] - mu; vs += d * d; }
    #pragma unroll
    for (int m = 1; m < 64; m <<= 1) vs += __shfl_xor(vs, m, 64);
    const float rs = rsqrtf(vs * (1.0f / 512.0f) + 1e-6f) * sc;

    float4 g0 = *reinterpret_cast<const float4*>(&gamma[lane * 8]);
    float4 g1 = *reinterpret_cast<const float4*>(&gamma[lane * 8 + 4]);
    float g[8] = {g0.x, g0.y, g0.z, g0.w, g1.x, g1.y, g1.z, g1.w};

    float y[8];
    #pragma unroll
    for (int i = 0; i < 8; ++i) y[i] = (x[i] - mu) * rs * g[i];
    uint4 o = make_uint4(cvtpk(y[0], y[1]), cvtpk(y[2], y[3]),
                         cvtpk(y[4], y[5]), cvtpk(y[6], y[7]));
    *reinterpret_cast<uint4*>(&Y[(size_t)row * DM + lane * 8]) = o;
}

// ---------------------------------------------------------------------------
// V [T*M][512] f32 -> Vt [T][512 dv][256 key] bf16
// ---------------------------------------------------------------------------
__global__ __launch_bounds__(256) void vtrans(const float* __restrict__ V,
                                              unsigned short* __restrict__ Vt) {
    const int t = blockIdx.z, kt = blockIdx.y, dt = blockIdx.x;
    __shared__ float tile[64][65];
    const int tid = threadIdx.x;

    #pragma unroll
    for (int i = 0; i < 4; ++i) {
        int idx = tid + i * 256;
        int r = idx >> 4, c4 = idx & 15;
        float4 v = *reinterpret_cast<const float4*>(
            &V[(size_t)(t * M_ + kt * 64 + r) * DM + dt * 64 + c4 * 4]);
        tile[r][c4 * 4 + 0] = v.x;
        tile[r][c4 * 4 + 1] = v.y;
        tile[r][c4 * 4 + 2] = v.z;
        tile[r][c4 * 4 + 3] = v.w;
    }
    __syncthreads();
    #pragma unroll
    for (int i = 0; i < 4; ++i) {
        int idx = tid + i * 256;
        int r = idx >> 4, c4 = idx & 15;
        uint2 o = make_uint2(cvtpk(tile[c4 * 4 + 0][r], tile[c4 * 4 + 1][r]),
                             cvtpk(tile[c4 * 4 + 2][r], tile[c4 * 4 + 3][r]));
        *reinterpret_cast<uint2*>(
            &Vt[((size_t)t * DM + dt * 64 + r) * M_ + kt * 64 + c4 * 4]) = o;
    }
}

// ---------------------------------------------------------------------------
// MFMA attention.  Scores^T layout: lane's softmax row is q = wq*16+c.
// After PV MFMA, output row is q = wq*16+g*4+r  =>  the deferred 1/sum must
// be SHUFFLED from the lane holding that row (c' = g*4+r).  [round-6/7/8 bug]
// ---------------------------------------------------------------------------
__global__ __launch_bounds__(256, 4) void attn_mfma(const unsigned short* __restrict__ Qbf,
                                                    const unsigned short* __restrict__ Kbf,
                                                    const unsigned short* __restrict__ VtG,
                                                    const float* __restrict__ tracks,
                                                    const float* __restrict__ fpos,
                                                    unsigned short* __restrict__ Ubf) {
    const int b   = blockIdx.x;
    const int xcd = b & 7;
    const int bi  = b >> 3;
    const int qt  = bi & 15;
    const int pp  = xcd + (bi >> 4) * 8;   // 0..127 = t*8 + h
    const int t   = pp >> 3;
    const int h   = pp & 7;
    const int q0  = qt * 64;
    const int tid = threadIdx.x;

    __shared__ __align__(16) unsigned char smem[32768 + 3072 + 512];
    unsigned char* KV = smem;                        // K [256k][64d] / V [64dv][256k]
    float* tx4 = (float*)(smem + 32768);             // 256: 4*log2e*tx
    float* ty4 = (float*)(smem + 32768 + 1024);      // 256: 4*log2e*ty
    float* tz2 = (float*)(smem + 32768 + 2048);      // 256: -2*log2e*|t|^2
    float* fps = (float*)(smem + 32768 + 3072);      // 64 x {x,y}

    // ---- stage K via global_load_lds (pre-swizzled source, linear dest) ----
    #pragma unroll
    for (int it = 0; it < 8; ++it) {
        int idx = tid + it * 256;               // 0..2047
        int row = idx >> 3, jj = idx & 7;
        int j = jj ^ (row & 7);
        gload16(Kbf + (size_t)(t * M_ + row) * DM + h * HEAD_ + j * 8, KV + idx * 16);
    }
    {
        float2 tk = *reinterpret_cast<const float2*>(&tracks[t * 512 + tid * 2]);
        tx4[tid] = tk.x * (4.0f * LOG2E);
        ty4[tid] = tk.y * (4.0f * LOG2E);
        tz2[tid] = -2.0f * LOG2E * (tk.x * tk.x + tk.y * tk.y);
    }
    if (tid < 128) fps[tid] = fpos[q0 * 2 + tid];
    __syncthreads();

    const int l  = tid & 63;
    const int wq = tid >> 6;
    const int g  = l >> 4;     // 0..3
    const int c  = l & 15;     // 0..15

    // ---- Q B-fragments direct from global ----
    const unsigned short* qrow =
        Qbf + (size_t)(t * HW_ + q0 + wq * 16 + c) * DM + h * HEAD_;
    short8 bQ0 = *reinterpret_cast<const short8*>(qrow + g * 8);
    short8 bQ1 = *reinterpret_cast<const short8*>(qrow + 32 + g * 8);

    // ---- scores^T: acc[n][r] = S[key=n*16+g*4+r][q=wq*16+c] ----
    f32x4 acc[16];
    #pragma unroll
    for (int n = 0; n < 16; ++n) {
        int rk = n * 16 + c;
        short8 a0 = *reinterpret_cast<short8*>(KV + ((rk * 128 + g * 16) ^ ((rk & 7) << 4)));
        short8 a1 = *reinterpret_cast<short8*>(KV + ((rk * 128 + 64 + g * 16) ^ ((rk & 7) << 4)));
        f32x4 z = {0.f, 0.f, 0.f, 0.f};
        z = __builtin_amdgcn_mfma_f32_16x16x32_bf16(a0, bQ0, z, 0, 0, 0);
        z = __builtin_amdgcn_mfma_f32_16x16x32_bf16(a1, bQ1, z, 0, 0, 0);
        acc[n] = z;
    }

    // ---- bias: 2 fma + 1 add per element (log2e domain) ----
    const float fx = fps[(wq * 16 + c) * 2];
    const float fy = fps[(wq * 16 + c) * 2 + 1];
    #pragma unroll
    for (int n = 0; n < 16; ++n) {
        float4 x4 = *reinterpret_cast<float4*>(&tx4[n * 16 + g * 4]);
        float4 y4 = *reinterpret_cast<float4*>(&ty4[n * 16 + g * 4]);
        float4 z4 = *reinterpret_cast<float4*>(&tz2[n * 16 + g * 4]);
        acc[n][0] += fmaf(fx, x4.x, fmaf(fy, y4.x, z4.x));
        acc[n][1] += fmaf(fx, x4.y, fmaf(fy, y4.y, z4.y));
        acc[n][2] += fmaf(fx, x4.z, fmaf(fy, y4.z, z4.z));
        acc[n][3] += fmaf(fx, x4.w, fmaf(fy, y4.w, z4.w));
    }

    // ---- max: tree reduce + cross-g shfl ----
    float vr[16];
    #pragma unroll
    for (int n = 0; n < 16; ++n)
        vr[n] = fmaxf(fmaxf(acc[n][0], acc[n][1]), fmaxf(acc[n][2], acc[n][3]));
    #pragma unroll
    for (int s = 8; s >= 1; s >>= 1)
        #pragma unroll
        for (int n = 0; n < 8; ++n)
            if (n < s) vr[n] = fmaxf(vr[n], vr[n + s]);
    float mx = vr[0];
    mx = fmaxf(mx, __shfl_xor(mx, 16, 64));
    mx = fmaxf(mx, __shfl_xor(mx, 32, 64));

    // ---- exp2 + pack P (unnormalized) ----
    #pragma unroll
    for (int n = 0; n < 16; ++n)
        #pragma unroll
        for (int r = 0; r < 4; ++r)
            acc[n][r] = exp2f(acc[n][r] - mx);

    unsigned pk[16][2];
    #pragma unroll
    for (int n = 0; n < 16; ++n) {
        pk[n][0] = cvtpk(acc[n][0], acc[n][1]);
        pk[n][1] = cvtpk(acc[n][2], acc[n][3]);
    }

    __syncthreads();   // all waves done with K -> overwrite with V

    // ---- stage V via global_load_lds ----
    #pragma unroll
    for (int it = 0; it < 8; ++it) {
        int idx = tid + it * 256;               // 0..2047
        int row = idx >> 5, kcc = idx & 31;
        int kc = kcc ^ (row & 7);
        gload16(VtG + ((size_t)t * DM + h * HEAD_ + row) * M_ + kc * 8, KV + idx * 16);
    }

    // ---- sum tree (overlaps V-load latency); inv applied at output ----
    #pragma unroll
    for (int n = 0; n < 16; ++n)
        vr[n] = (acc[n][0] + acc[n][1]) + (acc[n][2] + acc[n][3]);
    #pragma unroll
    for (int s = 8; s >= 1; s >>= 1)
        #pragma unroll
        for (int n = 0; n < 8; ++n)
            if (n < s) vr[n] += vr[n + s];
    float sum = vr[0];
    sum += __shfl_xor(sum, 16, 64);
    sum += __shfl_xor(sum, 32, 64);
    const float inv = 1.0f / sum;    // row q = wq*16 + c

    // FIX: output rows are q = wq*16 + g*4 + r -> fetch inv from lane c'=g*4+r
    float invr[4];
    #pragma unroll
    for (int r = 0; r < 4; ++r)
        invr[r] = __shfl(inv, (l & 48) | ((l >> 2) & 12) | r, 64);

    __syncthreads();

    // ---- PV ----
    f32x4 o[4] = {{0.f,0.f,0.f,0.f},{0.f,0.f,0.f,0.f},{0.f,0.f,0.f,0.f},{0.f,0.f,0.f,0.f}};
    #pragma unroll
    for (int ks = 0; ks < 8; ++ks) {
        unsigned wb[4];
        #pragma unroll
        for (int wt = 0; wt < 4; ++wt) {
            int src = ((l & 16) << 1) + (wt >> 1) * 16 + c;
            unsigned ve = (unsigned)__shfl((int)pk[2 * ks][wt & 1], src, 64);
            unsigned vo = (unsigned)__shfl((int)pk[2 * ks + 1][wt & 1], src, 64);
            wb[wt] = (g < 2) ? ve : vo;
        }
        uint4 uu = make_uint4(wb[0], wb[1], wb[2], wb[3]);
        short8 aP = *reinterpret_cast<short8*>(&uu);
        #pragma unroll
        for (int nv = 0; nv < 4; ++nv) {
            int rv = nv * 16 + c;
            short8 bV = *reinterpret_cast<short8*>(
                KV + ((rv * 512 + ks * 64 + g * 16) ^ ((rv & 7) << 4)));
            o[nv] = __builtin_amdgcn_mfma_f32_16x16x32_bf16(aP, bV, o[nv], 0, 0, 0);
        }
    }

    // ---- scale by the CORRECT row reciprocal, store U bf16 ----
    #pragma unroll
    for (int nv = 0; nv < 4; ++nv)
        #pragma unroll
        for (int r = 0; r < 4; ++r) {
            float x = o[nv][r] * invr[r];
            Ubf[(size_t)(t * HW_ + q0 + wq * 16 + g * 4 + r) * DM +
                h * HEAD_ + nv * 16 + c] = (unsigned short)cvtpk(x, x);
        }
}

// ---------------------------------------------------------------------------
extern "C" void kernel_launch(void* const* d_in, const int* in_sizes, int n_in,
                              void* d_out, int out_size, void* d_ws, size_t ws_size,
                              hipStream_t stream) {
    const float* utt    = (const float*)d_in[0];
    const float* tracks = (const float*)d_in[1];
    const float* fpos   = (const float*)d_in[2];
    const float* fpe    = (const float*)d_in[3];
    const float* tpe    = (const float*)d_in[4];
    const float* Wq     = (const float*)d_in[5];
    const float* Wk     = (const float*)d_in[6];
    const float* Wv     = (const float*)d_in[7];
    const float* Wo     = (const float*)d_in[8];
    const float* qgamma = (const float*)d_in[9];
    const float* kgamma = (const float*)d_in[10];
    float* out = (float*)d_out;

    char* ws = (char*)d_ws;
    float*          Qf  = (float*)(ws);                       // [0, 33.5M)
    float*          Kf  = (float*)(ws + 33554432);            // [33.5, 41.9)
    float*          Vf  = (float*)(ws + 41943040);            // [41.9, 50.3)
    unsigned short* Qbf = (unsigned short*)(ws + 33554432);   // overlays Kf+Vf
    unsigned short* Ubf = (unsigned short*)(ws + 50331648);   // [50.3, 67.1)
    unsigned short* Vt  = (unsigned short*)(ws + 67108864);   // [67.1, 71.3)
    unsigned short* Kbf = (unsigned short*)(ws + 71303168);   // [71.3, 75.5)
    unsigned short* Wbf = (unsigned short*)(ws + 75497472);   // 4 x 0.5MB

    // Weights -> bf16 (Wq,Wk,Wv,Wo)
    cvtw<<<dim3(128, 4), 256, 0, stream>>>(Wq, Wk, Wv, Wo, Wbf);

    // Projections
    gemm_fw<<<dim3(4, 128, 1), 256, 0, stream>>>(fpe, Wbf, Qf, fpe, Wbf, Qf);
    gemm_fw<<<dim3(4, 32, 2), 256, 0, stream>>>(tpe, Wbf + 262144, Kf,
                                                utt, Wbf + 524288, Vf);

    // V transpose+cast (before LN-Q overwrites Vf region)
    vtrans<<<dim3(8, 4, 16), 256, 0, stream>>>(Vf, Vt);

    // LayerNorm -> bf16 (K first; Q folds 0.125*log2e)
    ln_rows_bf16<<<1024, 256, 0, stream>>>(Kf, kgamma, Kbf, 4096, 1.0f);
    ln_rows_bf16<<<4096, 256, 0, stream>>>(Qf, qgamma, Qbf, 16384, 0.125f * LOG2E);

    // Fused MFMA attention -> bf16 U
    attn_mfma<<<2048, 256, 0, stream>>>(Qbf, Kbf, Vt, tracks, fpos, Ubf);

    // Out projection (bf16 x bf16)
    gemm_bb<<<dim3(4, 128), 256, 0, stream>>>(Ubf, Wbf + 786432, out);
}

// Round 10
// 115.186 us; speedup vs baseline: 11.3078x; 1.0614x over previous
//
#include <hip/hip_runtime.h>

#define T_    16
#define M_    256
#define HW_   1024
#define DM    512
#define H_    8
#define HEAD_ 64
#define LOG2E 1.4426950408889634f

typedef __attribute__((ext_vector_type(8))) short short8;
typedef __attribute__((ext_vector_type(4))) float f32x4;

__device__ __forceinline__ unsigned cvtpk(float lo, float hi) {
    unsigned r;
    asm("v_cvt_pk_bf16_f32 %0, %1, %2" : "=v"(r) : "v"(lo), "v"(hi));
    return r;
}

__device__ __forceinline__ void gload16(const void* g, void* l) {
    __builtin_amdgcn_global_load_lds(
        (const __attribute__((address_space(1))) void*)g,
        (__attribute__((address_space(3))) void*)l, 16, 0, 0);
}

// ---------------------------------------------------------------------------
// Merged Q/K/V projections: C = X(f32) @ W(f32->bf16 inline)^T.
// 768 blocks: [0,512) Q, [512,640) K, [640,768) V.  128x128 tile, BK=64.
// ---------------------------------------------------------------------------
__global__ __launch_bounds__(256) void proj3(const float* __restrict__ fpe,
                                             const float* __restrict__ tpe,
                                             const float* __restrict__ utt,
                                             const float* __restrict__ Wq,
                                             const float* __restrict__ Wk,
                                             const float* __restrict__ Wv,
                                             float* __restrict__ Qf,
                                             float* __restrict__ Kf,
                                             float* __restrict__ Vf) {
    __shared__ __align__(16) unsigned char smem[32768];
    unsigned char* As = smem;
    unsigned char* Bs = smem + 16384;

    const int bid = blockIdx.x;
    const float *X, *W;
    float* C;
    int b2;
    if (bid < 512)      { X = fpe; W = Wq; C = Qf; b2 = bid; }
    else if (bid < 640) { X = tpe; W = Wk; C = Kf; b2 = bid - 512; }
    else                { X = utt; W = Wv; C = Vf; b2 = bid - 640; }
    const int r0 = (b2 >> 2) * 128;
    const int c0 = (b2 & 3) * 128;

    const int tid = threadIdx.x;
    const int l  = tid & 63;
    const int wid = tid >> 6;
    const int wr = wid >> 1, wc = wid & 1;
    const int g = l >> 4;
    const int c = l & 15;

    f32x4 acc[4][4] = {};

    for (int k0 = 0; k0 < DM; k0 += 64) {
        #pragma unroll
        for (int i = 0; i < 4; ++i) {
            int idx = tid + i * 256;
            int row = idx >> 3, dc = idx & 7;
            const unsigned off = (unsigned)((row * 128 + dc * 16) ^ ((row & 7) << 4));
            {
                const float* s = X + (size_t)(r0 + row) * DM + k0 + dc * 8;
                float4 a = *reinterpret_cast<const float4*>(s);
                float4 b = *reinterpret_cast<const float4*>(s + 4);
                uint4 v = make_uint4(cvtpk(a.x, a.y), cvtpk(a.z, a.w),
                                     cvtpk(b.x, b.y), cvtpk(b.z, b.w));
                *reinterpret_cast<uint4*>(As + off) = v;
            }
            {
                const float* s = W + (size_t)(c0 + row) * DM + k0 + dc * 8;
                float4 a = *reinterpret_cast<const float4*>(s);
                float4 b = *reinterpret_cast<const float4*>(s + 4);
                uint4 v = make_uint4(cvtpk(a.x, a.y), cvtpk(a.z, a.w),
                                     cvtpk(b.x, b.y), cvtpk(b.z, b.w));
                *reinterpret_cast<uint4*>(Bs + off) = v;
            }
        }
        __syncthreads();

        #pragma unroll
        for (int ks = 0; ks < 2; ++ks) {
            short8 af[4], bfr[4];
            #pragma unroll
            for (int m = 0; m < 4; ++m) {
                int rq = wr * 64 + m * 16 + c;
                af[m] = *reinterpret_cast<short8*>(
                    As + ((rq * 128 + ks * 64 + g * 16) ^ ((rq & 7) << 4)));
            }
            #pragma unroll
            for (int n = 0; n < 4; ++n) {
                int rn = wc * 64 + n * 16 + c;
                bfr[n] = *reinterpret_cast<short8*>(
                    Bs + ((rn * 128 + ks * 64 + g * 16) ^ ((rn & 7) << 4)));
            }
            #pragma unroll
            for (int m = 0; m < 4; ++m)
                #pragma unroll
                for (int n = 0; n < 4; ++n)
                    acc[m][n] = __builtin_amdgcn_mfma_f32_16x16x32_bf16(
                        af[m], bfr[n], acc[m][n], 0, 0, 0);
        }
        __syncthreads();
    }

    #pragma unroll
    for (int m = 0; m < 4; ++m)
        #pragma unroll
        for (int n = 0; n < 4; ++n)
            #pragma unroll
            for (int r = 0; r < 4; ++r)
                C[(size_t)(r0 + wr * 64 + m * 16 + g * 4 + r) * DM +
                  c0 + wc * 64 + n * 16 + c] = acc[m][n][r];
}

// ---------------------------------------------------------------------------
// Out-projection: C = X(bf16 via gload16) @ W(f32->bf16 inline)^T.
// ---------------------------------------------------------------------------
__global__ __launch_bounds__(256) void gemm_bw(const unsigned short* __restrict__ X,
                                               const float* __restrict__ W,
                                               float* __restrict__ C) {
    __shared__ __align__(16) unsigned char smem[32768];
    unsigned char* As = smem;
    unsigned char* Bs = smem + 16384;

    const int tid = threadIdx.x;
    const int r0 = blockIdx.y * 128;
    const int c0 = blockIdx.x * 128;

    const int l  = tid & 63;
    const int wid = tid >> 6;
    const int wr = wid >> 1, wc = wid & 1;
    const int g = l >> 4;
    const int c = l & 15;

    f32x4 acc[4][4] = {};

    for (int k0 = 0; k0 < DM; k0 += 64) {
        #pragma unroll
        for (int i = 0; i < 4; ++i) {
            int idx = tid + i * 256;
            int row = idx >> 3, jj = idx & 7;
            int j = jj ^ (row & 7);
            gload16(X + (size_t)(r0 + row) * DM + k0 + j * 8, As + idx * 16);
            {
                const unsigned off = (unsigned)((row * 128 + jj * 16) ^ ((row & 7) << 4));
                const float* s = W + (size_t)(c0 + row) * DM + k0 + jj * 8;
                float4 a = *reinterpret_cast<const float4*>(s);
                float4 b = *reinterpret_cast<const float4*>(s + 4);
                uint4 v = make_uint4(cvtpk(a.x, a.y), cvtpk(a.z, a.w),
                                     cvtpk(b.x, b.y), cvtpk(b.z, b.w));
                *reinterpret_cast<uint4*>(Bs + off) = v;
            }
        }
        __syncthreads();

        #pragma unroll
        for (int ks = 0; ks < 2; ++ks) {
            short8 af[4], bfr[4];
            #pragma unroll
            for (int m = 0; m < 4; ++m) {
                int rq = wr * 64 + m * 16 + c;
                af[m] = *reinterpret_cast<short8*>(
                    As + ((rq * 128 + ks * 64 + g * 16) ^ ((rq & 7) << 4)));
            }
            #pragma unroll
            for (int n = 0; n < 4; ++n) {
                int rn = wc * 64 + n * 16 + c;
                bfr[n] = *reinterpret_cast<short8*>(
                    Bs + ((rn * 128 + ks * 64 + g * 16) ^ ((rn & 7) << 4)));
            }
            #pragma unroll
            for (int m = 0; m < 4; ++m)
                #pragma unroll
                for (int n = 0; n < 4; ++n)
                    acc[m][n] = __builtin_amdgcn_mfma_f32_16x16x32_bf16(
                        af[m], bfr[n], acc[m][n], 0, 0, 0);
        }
        __syncthreads();
    }

    #pragma unroll
    for (int m = 0; m < 4; ++m)
        #pragma unroll
        for (int n = 0; n < 4; ++n)
            #pragma unroll
            for (int r = 0; r < 4; ++r)
                C[(size_t)(r0 + wr * 64 + m * 16 + g * 4 + r) * DM +
                  c0 + wc * 64 + n * 16 + c] = acc[m][n][r];
}

// ---------------------------------------------------------------------------
// Merged normalize/pack launch: 5632 blocks.
//  [0,4096): LN-Q f32->bf16 (sc=0.125*log2e);  [4096,5120): LN-K;
//  [5120,5632): vtrans Vf -> Vt.
// ---------------------------------------------------------------------------
__global__ __launch_bounds__(256) void normpack(const float* __restrict__ Qf,
                                                const float* __restrict__ Kf,
                                                const float* __restrict__ Vf,
                                                const float* __restrict__ qg,
                                                const float* __restrict__ kg,
                                                unsigned short* __restrict__ Qbf,
                                                unsigned short* __restrict__ Kbf,
                                                unsigned short* __restrict__ Vt) {
    __shared__ float tile[64][65];
    const int bid = blockIdx.x;
    const int tid = threadIdx.x;

    if (bid < 5120) {
        const float* X; const float* gamma; unsigned short* Y; int rowbase; float sc;
        if (bid < 4096) { X = Qf; gamma = qg; Y = Qbf; rowbase = bid * 4; sc = 0.125f * LOG2E; }
        else            { X = Kf; gamma = kg; Y = Kbf; rowbase = (bid - 4096) * 4; sc = 1.0f; }

        const int wave = tid / 64;
        const int lane = tid % 64;
        const int row  = rowbase + wave;

        float4 v0 = *reinterpret_cast<const float4*>(&X[(size_t)row * DM + lane * 8]);
        float4 v1 = *reinterpret_cast<const float4*>(&X[(size_t)row * DM + lane * 8 + 4]);
        float x[8] = {v0.x, v0.y, v0.z, v0.w, v1.x, v1.y, v1.z, v1.w};

        float s = 0.f;
        #pragma unroll
        for (int i = 0; i < 8; ++i) s += x[i];
        #pragma unroll
        for (int m = 1; m < 64; m <<= 1) s += __shfl_xor(s, m, 64);
        const float mu = s * (1.0f / 512.0f);

        float vs = 0.f;
        #pragma unroll
        for (int i = 0; i < 8; ++i) { float d = x[i] - mu; vs += d * d; }
        #pragma unroll
        for (int m = 1; m < 64; m <<= 1) vs += __shfl_xor(vs, m, 64);
        const float rs = rsqrtf(vs * (1.0f / 512.0f) + 1e-6f) * sc;

        float4 g0 = *reinterpret_cast<const float4*>(&gamma[lane * 8]);
        float4 g1 = *reinterpret_cast<const float4*>(&gamma[lane * 8 + 4]);
        float gv[8] = {g0.x, g0.y, g0.z, g0.w, g1.x, g1.y, g1.z, g1.w};

        float y[8];
        #pragma unroll
        for (int i = 0; i < 8; ++i) y[i] = (x[i] - mu) * rs * gv[i];
        uint4 o = make_uint4(cvtpk(y[0], y[1]), cvtpk(y[2], y[3]),
                             cvtpk(y[4], y[5]), cvtpk(y[6], y[7]));
        *reinterpret_cast<uint4*>(&Y[(size_t)row * DM + lane * 8]) = o;
    } else {
        const int b2 = bid - 5120;
        const int dt = b2 & 7, kt = (b2 >> 3) & 3, t = b2 >> 5;

        #pragma unroll
        for (int i = 0; i < 4; ++i) {
            int idx = tid + i * 256;
            int r = idx >> 4, c4 = idx & 15;
            float4 v = *reinterpret_cast<const float4*>(
                &Vf[(size_t)(t * M_ + kt * 64 + r) * DM + dt * 64 + c4 * 4]);
            tile[r][c4 * 4 + 0] = v.x;
            tile[r][c4 * 4 + 1] = v.y;
            tile[r][c4 * 4 + 2] = v.z;
            tile[r][c4 * 4 + 3] = v.w;
        }
        __syncthreads();
        #pragma unroll
        for (int i = 0; i < 4; ++i) {
            int idx = tid + i * 256;
            int r = idx >> 4, c4 = idx & 15;
            uint2 o = make_uint2(cvtpk(tile[c4 * 4 + 0][r], tile[c4 * 4 + 1][r]),
                                 cvtpk(tile[c4 * 4 + 2][r], tile[c4 * 4 + 3][r]));
            *reinterpret_cast<uint2*>(
                &Vt[((size_t)t * DM + dt * 64 + r) * M_ + kt * 64 + c4 * 4]) = o;
        }
    }
}

// ---------------------------------------------------------------------------
// MFMA attention (round-9 verified math) + Q-hoist + setprio.
// ---------------------------------------------------------------------------
__global__ __launch_bounds__(256, 4) void attn_mfma(const unsigned short* __restrict__ Qbf,
                                                    const unsigned short* __restrict__ Kbf,
                                                    const unsigned short* __restrict__ VtG,
                                                    const float* __restrict__ tracks,
                                                    const float* __restrict__ fpos,
                                                    unsigned short* __restrict__ Ubf) {
    const int b   = blockIdx.x;
    const int xcd = b & 7;
    const int bi  = b >> 3;
    const int qt  = bi & 15;
    const int pp  = xcd + (bi >> 4) * 8;   // 0..127 = t*8 + h
    const int t   = pp >> 3;
    const int h   = pp & 7;
    const int q0  = qt * 64;
    const int tid = threadIdx.x;

    __shared__ __align__(16) unsigned char smem[32768 + 3072 + 512];
    unsigned char* KV = smem;                        // K [256k][64d] / V [64dv][256k]
    float* tx4 = (float*)(smem + 32768);
    float* ty4 = (float*)(smem + 32768 + 1024);
    float* tz2 = (float*)(smem + 32768 + 2048);
    float* fps = (float*)(smem + 32768 + 3072);

    const int l  = tid & 63;
    const int wq = tid >> 6;
    const int g  = l >> 4;     // 0..3
    const int c  = l & 15;     // 0..15

    // ---- Q B-fragments: issue BEFORE K staging (latency overlap) ----
    const unsigned short* qrow =
        Qbf + (size_t)(t * HW_ + q0 + wq * 16 + c) * DM + h * HEAD_;
    short8 bQ0 = *reinterpret_cast<const short8*>(qrow + g * 8);
    short8 bQ1 = *reinterpret_cast<const short8*>(qrow + 32 + g * 8);

    // ---- stage K via global_load_lds (pre-swizzled source, linear dest) ----
    #pragma unroll
    for (int it = 0; it < 8; ++it) {
        int idx = tid + it * 256;               // 0..2047
        int row = idx >> 3, jj = idx & 7;
        int j = jj ^ (row & 7);
        gload16(Kbf + (size_t)(t * M_ + row) * DM + h * HEAD_ + j * 8, KV + idx * 16);
    }
    {
        float2 tk = *reinterpret_cast<const float2*>(&tracks[t * 512 + tid * 2]);
        tx4[tid] = tk.x * (4.0f * LOG2E);
        ty4[tid] = tk.y * (4.0f * LOG2E);
        tz2[tid] = -2.0f * LOG2E * (tk.x * tk.x + tk.y * tk.y);
    }
    if (tid < 128) fps[tid] = fpos[q0 * 2 + tid];
    __syncthreads();

    // ---- scores^T: acc[n][r] = S[key=n*16+g*4+r][q=wq*16+c] ----
    f32x4 acc[16];
    __builtin_amdgcn_s_setprio(1);
    #pragma unroll
    for (int n = 0; n < 16; ++n) {
        int rk = n * 16 + c;
        short8 a0 = *reinterpret_cast<short8*>(KV + ((rk * 128 + g * 16) ^ ((rk & 7) << 4)));
        short8 a1 = *reinterpret_cast<short8*>(KV + ((rk * 128 + 64 + g * 16) ^ ((rk & 7) << 4)));
        f32x4 z = {0.f, 0.f, 0.f, 0.f};
        z = __builtin_amdgcn_mfma_f32_16x16x32_bf16(a0, bQ0, z, 0, 0, 0);
        z = __builtin_amdgcn_mfma_f32_16x16x32_bf16(a1, bQ1, z, 0, 0, 0);
        acc[n] = z;
    }
    __builtin_amdgcn_s_setprio(0);

    // ---- bias (log2e domain) ----
    const float fx = fps[(wq * 16 + c) * 2];
    const float fy = fps[(wq * 16 + c) * 2 + 1];
    #pragma unroll
    for (int n = 0; n < 16; ++n) {
        float4 x4 = *reinterpret_cast<float4*>(&tx4[n * 16 + g * 4]);
        float4 y4 = *reinterpret_cast<float4*>(&ty4[n * 16 + g * 4]);
        float4 z4 = *reinterpret_cast<float4*>(&tz2[n * 16 + g * 4]);
        acc[n][0] += fmaf(fx, x4.x, fmaf(fy, y4.x, z4.x));
        acc[n][1] += fmaf(fx, x4.y, fmaf(fy, y4.y, z4.y));
        acc[n][2] += fmaf(fx, x4.z, fmaf(fy, y4.z, z4.z));
        acc[n][3] += fmaf(fx, x4.w, fmaf(fy, y4.w, z4.w));
    }

    // ---- max: tree reduce + cross-g shfl ----
    float vr[16];
    #pragma unroll
    for (int n = 0; n < 16; ++n)
        vr[n] = fmaxf(fmaxf(acc[n][0], acc[n][1]), fmaxf(acc[n][2], acc[n][3]));
    #pragma unroll
    for (int s = 8; s >= 1; s >>= 1)
        #pragma unroll
        for (int n = 0; n < 8; ++n)
            if (n < s) vr[n] = fmaxf(vr[n], vr[n + s]);
    float mx = vr[0];
    mx = fmaxf(mx, __shfl_xor(mx, 16, 64));
    mx = fmaxf(mx, __shfl_xor(mx, 32, 64));

    // ---- exp2 + pack P (unnormalized) ----
    #pragma unroll
    for (int n = 0; n < 16; ++n)
        #pragma unroll
        for (int r = 0; r < 4; ++r)
            acc[n][r] = exp2f(acc[n][r] - mx);

    unsigned pk[16][2];
    #pragma unroll
    for (int n = 0; n < 16; ++n) {
        pk[n][0] = cvtpk(acc[n][0], acc[n][1]);
        pk[n][1] = cvtpk(acc[n][2], acc[n][3]);
    }

    __syncthreads();   // all waves done with K -> overwrite with V

    // ---- stage V via global_load_lds ----
    #pragma unroll
    for (int it = 0; it < 8; ++it) {
        int idx = tid + it * 256;               // 0..2047
        int row = idx >> 5, kcc = idx & 31;
        int kc = kcc ^ (row & 7);
        gload16(VtG + ((size_t)t * DM + h * HEAD_ + row) * M_ + kc * 8, KV + idx * 16);
    }

    // ---- sum tree (overlaps V-load latency); inv applied at output ----
    #pragma unroll
    for (int n = 0; n < 16; ++n)
        vr[n] = (acc[n][0] + acc[n][1]) + (acc[n][2] + acc[n][3]);
    #pragma unroll
    for (int s = 8; s >= 1; s >>= 1)
        #pragma unroll
        for (int n = 0; n < 8; ++n)
            if (n < s) vr[n] += vr[n + s];
    float sum = vr[0];
    sum += __shfl_xor(sum, 16, 64);
    sum += __shfl_xor(sum, 32, 64);
    const float inv = 1.0f / sum;    // row q = wq*16 + c

    // output rows are q = wq*16 + g*4 + r -> fetch inv from lane c'=g*4+r
    float invr[4];
    #pragma unroll
    for (int r = 0; r < 4; ++r)
        invr[r] = __shfl(inv, (l & 48) | ((l >> 2) & 12) | r, 64);

    __syncthreads();

    // ---- PV ----
    f32x4 o[4] = {{0.f,0.f,0.f,0.f},{0.f,0.f,0.f,0.f},{0.f,0.f,0.f,0.f},{0.f,0.f,0.f,0.f}};
    __builtin_amdgcn_s_setprio(1);
    #pragma unroll
    for (int ks = 0; ks < 8; ++ks) {
        unsigned wb[4];
        #pragma unroll
        for (int wt = 0; wt < 4; ++wt) {
            int src = ((l & 16) << 1) + (wt >> 1) * 16 + c;
            unsigned ve = (unsigned)__shfl((int)pk[2 * ks][wt & 1], src, 64);
            unsigned vo = (unsigned)__shfl((int)pk[2 * ks + 1][wt & 1], src, 64);
            wb[wt] = (g < 2) ? ve : vo;
        }
        uint4 uu = make_uint4(wb[0], wb[1], wb[2], wb[3]);
        short8 aP = *reinterpret_cast<short8*>(&uu);
        #pragma unroll
        for (int nv = 0; nv < 4; ++nv) {
            int rv = nv * 16 + c;
            short8 bV = *reinterpret_cast<short8*>(
                KV + ((rv * 512 + ks * 64 + g * 16) ^ ((rv & 7) << 4)));
            o[nv] = __builtin_amdgcn_mfma_f32_16x16x32_bf16(aP, bV, o[nv], 0, 0, 0);
        }
    }
    __builtin_amdgcn_s_setprio(0);

    // ---- scale by the correct row reciprocal, store U bf16 ----
    #pragma unroll
    for (int nv = 0; nv < 4; ++nv)
        #pragma unroll
        for (int r = 0; r < 4; ++r) {
            float x = o[nv][r] * invr[r];
            Ubf[(size_t)(t * HW_ + q0 + wq * 16 + g * 4 + r) * DM +
                h * HEAD_ + nv * 16 + c] = (unsigned short)cvtpk(x, x);
        }
}

// ---------------------------------------------------------------------------
extern "C" void kernel_launch(void* const* d_in, const int* in_sizes, int n_in,
                              void* d_out, int out_size, void* d_ws, size_t ws_size,
                              hipStream_t stream) {
    const float* utt    = (const float*)d_in[0];
    const float* tracks = (const float*)d_in[1];
    const float* fpos   = (const float*)d_in[2];
    const float* fpe    = (const float*)d_in[3];
    const float* tpe    = (const float*)d_in[4];
    const float* Wq     = (const float*)d_in[5];
    const float* Wk     = (const float*)d_in[6];
    const float* Wv     = (const float*)d_in[7];
    const float* Wo     = (const float*)d_in[8];
    const float* qgamma = (const float*)d_in[9];
    const float* kgamma = (const float*)d_in[10];
    float* out = (float*)d_out;

    char* ws = (char*)d_ws;
    float*          Qf  = (float*)(ws);                       // [0, 33.5M)
    float*          Kf  = (float*)(ws + 33554432);            // [33.5, 41.9)
    float*          Vf  = (float*)(ws + 41943040);            // [41.9, 50.3)
    unsigned short* Qbf = (unsigned short*)(ws + 50331648);   // [50.3, 67.1)
    unsigned short* Kbf = (unsigned short*)(ws + 67108864);   // [67.1, 71.3)
    unsigned short* Vt  = (unsigned short*)(ws + 71303168);   // [71.3, 75.5)
    unsigned short* Ubf = (unsigned short*)(ws);              // overlays Qf (dead after normpack)

    // 1) Q/K/V projections (one launch, inline W cast)
    proj3<<<768, 256, 0, stream>>>(fpe, tpe, utt, Wq, Wk, Wv, Qf, Kf, Vf);

    // 2) LN-Q, LN-K, V-transpose (one launch; disjoint read/write sets)
    normpack<<<5632, 256, 0, stream>>>(Qf, Kf, Vf, qgamma, kgamma, Qbf, Kbf, Vt);

    // 3) Fused MFMA attention -> bf16 U (overlays dead Qf)
    attn_mfma<<<2048, 256, 0, stream>>>(Qbf, Kbf, Vt, tracks, fpos, Ubf);

    // 4) Out projection
    gemm_bw<<<dim3(4, 128), 256, 0, stream>>>(Ubf, Wo, out);
}

// Round 11
// 105.396 us; speedup vs baseline: 12.3581x; 1.0929x over previous
//
#include <hip/hip_runtime.h>

#define T_    16
#define M_    256
#define HW_   1024
#define DM    512
#define H_    8
#define HEAD_ 64
#define LOG2E 1.4426950408889634f

typedef __attribute__((ext_vector_type(8))) short short8;
typedef __attribute__((ext_vector_type(4))) float f32x4;

__device__ __forceinline__ unsigned cvtpk(float lo, float hi) {
    unsigned r;
    asm("v_cvt_pk_bf16_f32 %0, %1, %2" : "=v"(r) : "v"(lo), "v"(hi));
    return r;
}

__device__ __forceinline__ void gload16(const void* g, void* l) {
    __builtin_amdgcn_global_load_lds(
        (const __attribute__((address_space(1))) void*)g,
        (__attribute__((address_space(3))) void*)l, 16, 0, 0);
}

// ---------------------------------------------------------------------------
// Convert all f32 operands to bf16 in one memory-bound pass.
// Segments (elems): fpe 8388608 | tpe 2097152 | utt 2097152 | Wq..Wo 262144 ea
// 13631488 elems total -> 6656 blocks x 256 thr x 8 elems.
// ---------------------------------------------------------------------------
__global__ __launch_bounds__(256) void cvtall(const float* __restrict__ fpe,
                                              const float* __restrict__ tpe,
                                              const float* __restrict__ utt,
                                              const float* __restrict__ Wq,
                                              const float* __restrict__ Wk,
                                              const float* __restrict__ Wv,
                                              const float* __restrict__ Wo,
                                              unsigned short* __restrict__ Fb,
                                              unsigned short* __restrict__ Tb,
                                              unsigned short* __restrict__ Ub0,
                                              unsigned short* __restrict__ Wbf) {
    size_t e = (size_t)(blockIdx.x * 256 + threadIdx.x) * 8;
    const float* s;
    unsigned short* d;
    if (e < 8388608)        { s = fpe + e;              d = Fb  + e; }
    else if (e < 10485760)  { s = tpe + (e - 8388608);  d = Tb  + (e - 8388608); }
    else if (e < 12582912)  { s = utt + (e - 10485760); d = Ub0 + (e - 10485760); }
    else if (e < 12845056)  { s = Wq  + (e - 12582912); d = Wbf + (e - 12582912 + 0); }
    else if (e < 13107200)  { s = Wk  + (e - 12845056); d = Wbf + (e - 12845056 + 262144); }
    else if (e < 13369344)  { s = Wv  + (e - 13107200); d = Wbf + (e - 13107200 + 524288); }
    else                    { s = Wo  + (e - 13369344); d = Wbf + (e - 13369344 + 786432); }
    float4 a = *reinterpret_cast<const float4*>(s);
    float4 b = *reinterpret_cast<const float4*>(s + 4);
    uint4 v = make_uint4(cvtpk(a.x, a.y), cvtpk(a.z, a.w),
                         cvtpk(b.x, b.y), cvtpk(b.z, b.w));
    *reinterpret_cast<uint4*>(d) = v;
}

// ---------------------------------------------------------------------------
// Merged Q/K/V projections, all-bf16 operands, pure gload16 staging.
// 768 blocks, XCD-grouped: x=b&7 (XCD), panel p=x*24+(b>>5), col=(b>>3)&3.
// The 4 col-blocks of a panel share an XCD -> X panel L2-resident.
// ---------------------------------------------------------------------------
__global__ __launch_bounds__(256) void proj3(const unsigned short* __restrict__ Fb,
                                             const unsigned short* __restrict__ Tb,
                                             const unsigned short* __restrict__ Ub0,
                                             const unsigned short* __restrict__ Wbf,
                                             float* __restrict__ Qf,
                                             float* __restrict__ Kf,
                                             float* __restrict__ Vf) {
    __shared__ __align__(16) unsigned char smem[32768];
    unsigned char* As = smem;
    unsigned char* Bs = smem + 16384;

    const int b  = blockIdx.x;
    const int x  = b & 7;
    const int cp = (b >> 3) & 3;
    const int m  = b >> 5;            // 0..23
    const int p  = x * 24 + m;        // 0..191 unique
    const unsigned short *X, *W;
    float* C;
    int r0;
    if (p < 128)      { X = Fb;  W = Wbf;          C = Qf; r0 = p * 128; }
    else if (p < 160) { X = Tb;  W = Wbf + 262144; C = Kf; r0 = (p - 128) * 128; }
    else              { X = Ub0; W = Wbf + 524288; C = Vf; r0 = (p - 160) * 128; }
    const int c0 = cp * 128;

    const int tid = threadIdx.x;
    const int l  = tid & 63;
    const int wid = tid >> 6;
    const int wr = wid >> 1, wc = wid & 1;
    const int g = l >> 4;
    const int c = l & 15;

    f32x4 acc[4][4] = {};

    for (int k0 = 0; k0 < DM; k0 += 64) {
        #pragma unroll
        for (int i = 0; i < 4; ++i) {
            int idx = tid + i * 256;
            int row = idx >> 3, jj = idx & 7;
            int j = jj ^ (row & 7);
            gload16(X + (size_t)(r0 + row) * DM + k0 + j * 8, As + idx * 16);
            gload16(W + (size_t)(c0 + row) * DM + k0 + j * 8, Bs + idx * 16);
        }
        __syncthreads();

        #pragma unroll
        for (int ks = 0; ks < 2; ++ks) {
            short8 af[4], bfr[4];
            #pragma unroll
            for (int mm = 0; mm < 4; ++mm) {
                int rq = wr * 64 + mm * 16 + c;
                af[mm] = *reinterpret_cast<short8*>(
                    As + ((rq * 128 + ks * 64 + g * 16) ^ ((rq & 7) << 4)));
            }
            #pragma unroll
            for (int n = 0; n < 4; ++n) {
                int rn = wc * 64 + n * 16 + c;
                bfr[n] = *reinterpret_cast<short8*>(
                    Bs + ((rn * 128 + ks * 64 + g * 16) ^ ((rn & 7) << 4)));
            }
            #pragma unroll
            for (int mm = 0; mm < 4; ++mm)
                #pragma unroll
                for (int n = 0; n < 4; ++n)
                    acc[mm][n] = __builtin_amdgcn_mfma_f32_16x16x32_bf16(
                        af[mm], bfr[n], acc[mm][n], 0, 0, 0);
        }
        __syncthreads();
    }

    #pragma unroll
    for (int mm = 0; mm < 4; ++mm)
        #pragma unroll
        for (int n = 0; n < 4; ++n)
            #pragma unroll
            for (int r = 0; r < 4; ++r)
                C[(size_t)(r0 + wr * 64 + mm * 16 + g * 4 + r) * DM +
                  c0 + wc * 64 + n * 16 + c] = acc[mm][n][r];
}

// ---------------------------------------------------------------------------
// Out-projection: both operands bf16 via gload16; XCD-grouped 512 blocks.
// ---------------------------------------------------------------------------
__global__ __launch_bounds__(256) void gemm_bb(const unsigned short* __restrict__ X,
                                               const unsigned short* __restrict__ W,
                                               float* __restrict__ C) {
    __shared__ __align__(16) unsigned char smem[32768];
    unsigned char* As = smem;
    unsigned char* Bs = smem + 16384;

    const int b  = blockIdx.x;
    const int x  = b & 7;
    const int cp = (b >> 3) & 3;
    const int m  = b >> 5;            // 0..15
    const int p  = x * 16 + m;        // 0..127 unique
    const int r0 = p * 128;
    const int c0 = cp * 128;

    const int tid = threadIdx.x;
    const int l  = tid & 63;
    const int wid = tid >> 6;
    const int wr = wid >> 1, wc = wid & 1;
    const int g = l >> 4;
    const int c = l & 15;

    f32x4 acc[4][4] = {};

    for (int k0 = 0; k0 < DM; k0 += 64) {
        #pragma unroll
        for (int i = 0; i < 4; ++i) {
            int idx = tid + i * 256;
            int row = idx >> 3, jj = idx & 7;
            int j = jj ^ (row & 7);
            gload16(X + (size_t)(r0 + row) * DM + k0 + j * 8, As + idx * 16);
            gload16(W + (size_t)(c0 + row) * DM + k0 + j * 8, Bs + idx * 16);
        }
        __syncthreads();

        #pragma unroll
        for (int ks = 0; ks < 2; ++ks) {
            short8 af[4], bfr[4];
            #pragma unroll
            for (int mm = 0; mm < 4; ++mm) {
                int rq = wr * 64 + mm * 16 + c;
                af[mm] = *reinterpret_cast<short8*>(
                    As + ((rq * 128 + ks * 64 + g * 16) ^ ((rq & 7) << 4)));
            }
            #pragma unroll
            for (int n = 0; n < 4; ++n) {
                int rn = wc * 64 + n * 16 + c;
                bfr[n] = *reinterpret_cast<short8*>(
                    Bs + ((rn * 128 + ks * 64 + g * 16) ^ ((rn & 7) << 4)));
            }
            #pragma unroll
            for (int mm = 0; mm < 4; ++mm)
                #pragma unroll
                for (int n = 0; n < 4; ++n)
                    acc[mm][n] = __builtin_amdgcn_mfma_f32_16x16x32_bf16(
                        af[mm], bfr[n], acc[mm][n], 0, 0, 0);
        }
        __syncthreads();
    }

    #pragma unroll
    for (int mm = 0; mm < 4; ++mm)
        #pragma unroll
        for (int n = 0; n < 4; ++n)
            #pragma unroll
            for (int r = 0; r < 4; ++r)
                C[(size_t)(r0 + wr * 64 + mm * 16 + g * 4 + r) * DM +
                  c0 + wc * 64 + n * 16 + c] = acc[mm][n][r];
}

// ---------------------------------------------------------------------------
// Merged normalize/pack launch: 5632 blocks.
//  [0,4096): LN-Q f32->bf16 (sc=0.125*log2e);  [4096,5120): LN-K;
//  [5120,5632): vtrans Vf -> Vt.
// ---------------------------------------------------------------------------
__global__ __launch_bounds__(256) void normpack(const float* __restrict__ Qf,
                                                const float* __restrict__ Kf,
                                                const float* __restrict__ Vf,
                                                const float* __restrict__ qg,
                                                const float* __restrict__ kg,
                                                unsigned short* __restrict__ Qbf,
                                                unsigned short* __restrict__ Kbf,
                                                unsigned short* __restrict__ Vt) {
    __shared__ float tile[64][65];
    const int bid = blockIdx.x;
    const int tid = threadIdx.x;

    if (bid < 5120) {
        const float* X; const float* gamma; unsigned short* Y; int rowbase; float sc;
        if (bid < 4096) { X = Qf; gamma = qg; Y = Qbf; rowbase = bid * 4; sc = 0.125f * LOG2E; }
        else            { X = Kf; gamma = kg; Y = Kbf; rowbase = (bid - 4096) * 4; sc = 1.0f; }

        const int wave = tid / 64;
        const int lane = tid % 64;
        const int row  = rowbase + wave;

        float4 v0 = *reinterpret_cast<const float4*>(&X[(size_t)row * DM + lane * 8]);
        float4 v1 = *reinterpret_cast<const float4*>(&X[(size_t)row * DM + lane * 8 + 4]);
        float x[8] = {v0.x, v0.y, v0.z, v0.w, v1.x, v1.y, v1.z, v1.w};

        float s = 0.f;
        #pragma unroll
        for (int i = 0; i < 8; ++i) s += x[i];
        #pragma unroll
        for (int m = 1; m < 64; m <<= 1) s += __shfl_xor(s, m, 64);
        const float mu = s * (1.0f / 512.0f);

        float vs = 0.f;
        #pragma unroll
        for (int i = 0; i < 8; ++i) { float d = x[i] - mu; vs += d * d; }
        #pragma unroll
        for (int m = 1; m < 64; m <<= 1) vs += __shfl_xor(vs, m, 64);
        const float rs = rsqrtf(vs * (1.0f / 512.0f) + 1e-6f) * sc;

        float4 g0 = *reinterpret_cast<const float4*>(&gamma[lane * 8]);
        float4 g1 = *reinterpret_cast<const float4*>(&gamma[lane * 8 + 4]);
        float gv[8] = {g0.x, g0.y, g0.z, g0.w, g1.x, g1.y, g1.z, g1.w};

        float y[8];
        #pragma unroll
        for (int i = 0; i < 8; ++i) y[i] = (x[i] - mu) * rs * gv[i];
        uint4 o = make_uint4(cvtpk(y[0], y[1]), cvtpk(y[2], y[3]),
                             cvtpk(y[4], y[5]), cvtpk(y[6], y[7]));
        *reinterpret_cast<uint4*>(&Y[(size_t)row * DM + lane * 8]) = o;
    } else {
        const int b2 = bid - 5120;
        const int dt = b2 & 7, kt = (b2 >> 3) & 3, t = b2 >> 5;

        #pragma unroll
        for (int i = 0; i < 4; ++i) {
            int idx = tid + i * 256;
            int r = idx >> 4, c4 = idx & 15;
            float4 v = *reinterpret_cast<const float4*>(
                &Vf[(size_t)(t * M_ + kt * 64 + r) * DM + dt * 64 + c4 * 4]);
            tile[r][c4 * 4 + 0] = v.x;
            tile[r][c4 * 4 + 1] = v.y;
            tile[r][c4 * 4 + 2] = v.z;
            tile[r][c4 * 4 + 3] = v.w;
        }
        __syncthreads();
        #pragma unroll
        for (int i = 0; i < 4; ++i) {
            int idx = tid + i * 256;
            int r = idx >> 4, c4 = idx & 15;
            uint2 o = make_uint2(cvtpk(tile[c4 * 4 + 0][r], tile[c4 * 4 + 1][r]),
                                 cvtpk(tile[c4 * 4 + 2][r], tile[c4 * 4 + 3][r]));
            *reinterpret_cast<uint2*>(
                &Vt[((size_t)t * DM + dt * 64 + r) * M_ + kt * 64 + c4 * 4]) = o;
        }
    }
}

// ---------------------------------------------------------------------------
// MFMA attention (round-9 verified) + Q-hoist + setprio.
// ---------------------------------------------------------------------------
__global__ __launch_bounds__(256, 4) void attn_mfma(const unsigned short* __restrict__ Qbf,
                                                    const unsigned short* __restrict__ Kbf,
                                                    const unsigned short* __restrict__ VtG,
                                                    const float* __restrict__ tracks,
                                                    const float* __restrict__ fpos,
                                                    unsigned short* __restrict__ Ubf) {
    const int b   = blockIdx.x;
    const int xcd = b & 7;
    const int bi  = b >> 3;
    const int qt  = bi & 15;
    const int pp  = xcd + (bi >> 4) * 8;   // 0..127 = t*8 + h
    const int t   = pp >> 3;
    const int h   = pp & 7;
    const int q0  = qt * 64;
    const int tid = threadIdx.x;

    __shared__ __align__(16) unsigned char smem[32768 + 3072 + 512];
    unsigned char* KV = smem;                        // K [256k][64d] / V [64dv][256k]
    float* tx4 = (float*)(smem + 32768);
    float* ty4 = (float*)(smem + 32768 + 1024);
    float* tz2 = (float*)(smem + 32768 + 2048);
    float* fps = (float*)(smem + 32768 + 3072);

    const int l  = tid & 63;
    const int wq = tid >> 6;
    const int g  = l >> 4;     // 0..3
    const int c  = l & 15;     // 0..15

    // ---- Q B-fragments: issue BEFORE K staging (latency overlap) ----
    const unsigned short* qrow =
        Qbf + (size_t)(t * HW_ + q0 + wq * 16 + c) * DM + h * HEAD_;
    short8 bQ0 = *reinterpret_cast<const short8*>(qrow + g * 8);
    short8 bQ1 = *reinterpret_cast<const short8*>(qrow + 32 + g * 8);

    // ---- stage K via global_load_lds (pre-swizzled source, linear dest) ----
    #pragma unroll
    for (int it = 0; it < 8; ++it) {
        int idx = tid + it * 256;               // 0..2047
        int row = idx >> 3, jj = idx & 7;
        int j = jj ^ (row & 7);
        gload16(Kbf + (size_t)(t * M_ + row) * DM + h * HEAD_ + j * 8, KV + idx * 16);
    }
    {
        float2 tk = *reinterpret_cast<const float2*>(&tracks[t * 512 + tid * 2]);
        tx4[tid] = tk.x * (4.0f * LOG2E);
        ty4[tid] = tk.y * (4.0f * LOG2E);
        tz2[tid] = -2.0f * LOG2E * (tk.x * tk.x + tk.y * tk.y);
    }
    if (tid < 128) fps[tid] = fpos[q0 * 2 + tid];
    __syncthreads();

    // ---- scores^T: acc[n][r] = S[key=n*16+g*4+r][q=wq*16+c] ----
    f32x4 acc[16];
    __builtin_amdgcn_s_setprio(1);
    #pragma unroll
    for (int n = 0; n < 16; ++n) {
        int rk = n * 16 + c;
        short8 a0 = *reinterpret_cast<short8*>(KV + ((rk * 128 + g * 16) ^ ((rk & 7) << 4)));
        short8 a1 = *reinterpret_cast<short8*>(KV + ((rk * 128 + 64 + g * 16) ^ ((rk & 7) << 4)));
        f32x4 z = {0.f, 0.f, 0.f, 0.f};
        z = __builtin_amdgcn_mfma_f32_16x16x32_bf16(a0, bQ0, z, 0, 0, 0);
        z = __builtin_amdgcn_mfma_f32_16x16x32_bf16(a1, bQ1, z, 0, 0, 0);
        acc[n] = z;
    }
    __builtin_amdgcn_s_setprio(0);

    // ---- bias (log2e domain) ----
    const float fx = fps[(wq * 16 + c) * 2];
    const float fy = fps[(wq * 16 + c) * 2 + 1];
    #pragma unroll
    for (int n = 0; n < 16; ++n) {
        float4 x4 = *reinterpret_cast<float4*>(&tx4[n * 16 + g * 4]);
        float4 y4 = *reinterpret_cast<float4*>(&ty4[n * 16 + g * 4]);
        float4 z4 = *reinterpret_cast<float4*>(&tz2[n * 16 + g * 4]);
        acc[n][0] += fmaf(fx, x4.x, fmaf(fy, y4.x, z4.x));
        acc[n][1] += fmaf(fx, x4.y, fmaf(fy, y4.y, z4.y));
        acc[n][2] += fmaf(fx, x4.z, fmaf(fy, y4.z, z4.z));
        acc[n][3] += fmaf(fx, x4.w, fmaf(fy, y4.w, z4.w));
    }

    // ---- max: tree reduce + cross-g shfl ----
    float vr[16];
    #pragma unroll
    for (int n = 0; n < 16; ++n)
        vr[n] = fmaxf(fmaxf(acc[n][0], acc[n][1]), fmaxf(acc[n][2], acc[n][3]));
    #pragma unroll
    for (int s = 8; s >= 1; s >>= 1)
        #pragma unroll
        for (int n = 0; n < 8; ++n)
            if (n < s) vr[n] = fmaxf(vr[n], vr[n + s]);
    float mx = vr[0];
    mx = fmaxf(mx, __shfl_xor(mx, 16, 64));
    mx = fmaxf(mx, __shfl_xor(mx, 32, 64));

    // ---- exp2 + pack P (unnormalized) ----
    #pragma unroll
    for (int n = 0; n < 16; ++n)
        #pragma unroll
        for (int r = 0; r < 4; ++r)
            acc[n][r] = exp2f(acc[n][r] - mx);

    unsigned pk[16][2];
    #pragma unroll
    for (int n = 0; n < 16; ++n) {
        pk[n][0] = cvtpk(acc[n][0], acc[n][1]);
        pk[n][1] = cvtpk(acc[n][2], acc[n][3]);
    }

    __syncthreads();   // all waves done with K -> overwrite with V

    // ---- stage V via global_load_lds ----
    #pragma unroll
    for (int it = 0; it < 8; ++it) {
        int idx = tid + it * 256;               // 0..2047
        int row = idx >> 5, kcc = idx & 31;
        int kc = kcc ^ (row & 7);
        gload16(VtG + ((size_t)t * DM + h * HEAD_ + row) * M_ + kc * 8, KV + idx * 16);
    }

    // ---- sum tree (overlaps V-load latency); inv applied at output ----
    #pragma unroll
    for (int n = 0; n < 16; ++n)
        vr[n] = (acc[n][0] + acc[n][1]) + (acc[n][2] + acc[n][3]);
    #pragma unroll
    for (int s = 8; s >= 1; s >>= 1)
        #pragma unroll
        for (int n = 0; n < 8; ++n)
            if (n < s) vr[n] += vr[n + s];
    float sum = vr[0];
    sum += __shfl_xor(sum, 16, 64);
    sum += __shfl_xor(sum, 32, 64);
    const float inv = 1.0f / sum;    // row q = wq*16 + c

    // output rows are q = wq*16 + g*4 + r -> fetch inv from lane c'=g*4+r
    float invr[4];
    #pragma unroll
    for (int r = 0; r < 4; ++r)
        invr[r] = __shfl(inv, (l & 48) | ((l >> 2) & 12) | r, 64);

    __syncthreads();

    // ---- PV ----
    f32x4 o[4] = {{0.f,0.f,0.f,0.f},{0.f,0.f,0.f,0.f},{0.f,0.f,0.f,0.f},{0.f,0.f,0.f,0.f}};
    __builtin_amdgcn_s_setprio(1);
    #pragma unroll
    for (int ks = 0; ks < 8; ++ks) {
        unsigned wb[4];
        #pragma unroll
        for (int wt = 0; wt < 4; ++wt) {
            int src = ((l & 16) << 1) + (wt >> 1) * 16 + c;
            unsigned ve = (unsigned)__shfl((int)pk[2 * ks][wt & 1], src, 64);
            unsigned vo = (unsigned)__shfl((int)pk[2 * ks + 1][wt & 1], src, 64);
            wb[wt] = (g < 2) ? ve : vo;
        }
        uint4 uu = make_uint4(wb[0], wb[1], wb[2], wb[3]);
        short8 aP = *reinterpret_cast<short8*>(&uu);
        #pragma unroll
        for (int nv = 0; nv < 4; ++nv) {
            int rv = nv * 16 + c;
            short8 bV = *reinterpret_cast<short8*>(
                KV + ((rv * 512 + ks * 64 + g * 16) ^ ((rv & 7) << 4)));
            o[nv] = __builtin_amdgcn_mfma_f32_16x16x32_bf16(aP, bV, o[nv], 0, 0, 0);
        }
    }
    __builtin_amdgcn_s_setprio(0);

    // ---- scale by the correct row reciprocal, store U bf16 ----
    #pragma unroll
    for (int nv = 0; nv < 4; ++nv)
        #pragma unroll
        for (int r = 0; r < 4; ++r) {
            float x = o[nv][r] * invr[r];
            Ubf[(size_t)(t * HW_ + q0 + wq * 16 + g * 4 + r) * DM +
                h * HEAD_ + nv * 16 + c] = (unsigned short)cvtpk(x, x);
        }
}

// ---------------------------------------------------------------------------
extern "C" void kernel_launch(void* const* d_in, const int* in_sizes, int n_in,
                              void* d_out, int out_size, void* d_ws, size_t ws_size,
                              hipStream_t stream) {
    const float* utt    = (const float*)d_in[0];
    const float* tracks = (const float*)d_in[1];
    const float* fpos   = (const float*)d_in[2];
    const float* fpe    = (const float*)d_in[3];
    const float* tpe    = (const float*)d_in[4];
    const float* Wq     = (const float*)d_in[5];
    const float* Wk     = (const float*)d_in[6];
    const float* Wv     = (const float*)d_in[7];
    const float* Wo     = (const float*)d_in[8];
    const float* qgamma = (const float*)d_in[9];
    const float* kgamma = (const float*)d_in[10];
    float* out = (float*)d_out;

    char* ws = (char*)d_ws;
    float*          Qf  = (float*)(ws);                       // [0, 33.5M)
    float*          Kf  = (float*)(ws + 33554432);            // [33.5, 41.9)
    float*          Vf  = (float*)(ws + 41943040);            // [41.9, 50.3)
    unsigned short* Qbf = (unsigned short*)(ws + 50331648);   // [50.3, 67.1)
    unsigned short* Kbf = (unsigned short*)(ws + 67108864);   // [67.1, 71.3)
    unsigned short* Vt  = (unsigned short*)(ws + 71303168);   // [71.3, 75.5)
    unsigned short* Wbf = (unsigned short*)(ws + 75497472);   // [75.5, 77.6)
    // bf16 input copies overlay later-written buffers (dead by then):
    unsigned short* Fb  = Qbf;   // consumed by proj3; Qbf written in normpack
    unsigned short* Tb  = Kbf;   // consumed by proj3; Kbf written in normpack
    unsigned short* Ub0 = Vt;    // consumed by proj3; Vt written in normpack
    unsigned short* Ubf = (unsigned short*)(ws);              // overlays Qf (dead after normpack)

    // 1) all f32 -> bf16 conversions (memory-bound single pass)
    cvtall<<<6656, 256, 0, stream>>>(fpe, tpe, utt, Wq, Wk, Wv, Wo, Fb, Tb, Ub0, Wbf);

    // 2) Q/K/V projections (all-bf16, gload16 staging, XCD-grouped)
    proj3<<<768, 256, 0, stream>>>(Fb, Tb, Ub0, Wbf, Qf, Kf, Vf);

    // 3) LN-Q, LN-K, V-transpose (one launch)
    normpack<<<5632, 256, 0, stream>>>(Qf, Kf, Vf, qgamma, kgamma, Qbf, Kbf, Vt);

    // 4) Fused MFMA attention -> bf16 U (overlays dead Qf)
    attn_mfma<<<2048, 256, 0, stream>>>(Qbf, Kbf, Vt, tracks, fpos, Ubf);

    // 5) Out projection (both bf16 via gload16)
    gemm_bb<<<512, 256, 0, stream>>>(Ubf, Wbf + 786432, out);
}